// Round 3
// baseline (12070.730 us; speedup 1.0000x reference)
//
#include <hip/hip_runtime.h>
#include <cstdint>
#include <cstddef>

// Problem constants
#define SENC  128
#define NSTEPS 159          // 128 encoder + 31 decoder
#define HB    524288        // elements per packed-h buffer (512*1024 dwords)
#define SLAB_ELEMS 55296    // per-c weight slab: 36*3*64*8 shorts
#define FRAG_TOTAL 442368   // 64*36*3*64 fragment slots

typedef short  short8  __attribute__((ext_vector_type(8)));
typedef float  floatx4 __attribute__((ext_vector_type(4)));
typedef float  f32x4   __attribute__((ext_vector_type(4)));
typedef unsigned long long u64;

#define MFMA(a, b, c) __builtin_amdgcn_mfma_f32_16x16x32_bf16((a), (b), (c), 0, 0, 0)

// ---------- agent-scope relaxed atomics: sc0/sc1 accesses, coherent at L3,
// ---------- bypass L1/L2 => no cache fences needed anywhere ----------
__device__ __forceinline__ unsigned ldu_dev(const unsigned* p) {
    return __hip_atomic_load(p, __ATOMIC_RELAXED, __HIP_MEMORY_SCOPE_AGENT);
}
__device__ __forceinline__ u64 ldq_dev(const u64* p) {
    return __hip_atomic_load(p, __ATOMIC_RELAXED, __HIP_MEMORY_SCOPE_AGENT);
}
__device__ __forceinline__ void stu_dev(unsigned* p, unsigned v) {
    __hip_atomic_store(p, v, __ATOMIC_RELAXED, __HIP_MEMORY_SCOPE_AGENT);
}
__device__ __forceinline__ void stf_dev(float* p, float v) {
    __hip_atomic_store(p, v, __ATOMIC_RELAXED, __HIP_MEMORY_SCOPE_AGENT);
}

// ---------- bf16 helpers (RNE) ----------
__device__ __forceinline__ float bf2f(short s) {
    return __uint_as_float(((unsigned)(unsigned short)s) << 16);
}
__device__ __forceinline__ short f2bf(float f) {
    unsigned u = __float_as_uint(f);
    return (short)((u + 0x7FFFu + ((u >> 16) & 1u)) >> 16);
}
__device__ __forceinline__ void f2pair(float f, short& hi, short& lo) {
    hi = f2bf(f);
    lo = f2bf(f - bf2f(hi));
}

__device__ __forceinline__ float sigm(float x) {
    return 1.0f / (1.0f + __expf(-x));
}
__device__ __forceinline__ float tanh_fast(float x) {
    float cx = fminf(fmaxf(x, -15.0f), 15.0f);
    float e = __expf(2.0f * cx);
    return (e - 1.0f) / (e + 1.0f);
}

// ---------- fence-free r-group barrier (64 blocks) ----------
// All inter-block data goes through agent-scope atomics (already at the
// coherence point), so: drain own stores (vmcnt) -> count -> spin gen.
__device__ __forceinline__ void rbar(unsigned* cnt, unsigned* gen, unsigned epoch) {
    asm volatile("s_waitcnt vmcnt(0)" ::: "memory");
    __syncthreads();
    if (threadIdx.x == 0) {
        unsigned old = __hip_atomic_fetch_add(cnt, 1u, __ATOMIC_RELAXED, __HIP_MEMORY_SCOPE_AGENT);
        if (old == epoch * 64u + 63u) {
            stu_dev(gen, epoch + 1u);
        } else {
            while (ldu_dev(gen) <= epoch) __builtin_amdgcn_s_sleep(1);
        }
    }
    __syncthreads();
}

// ---------- setup: swizzle [Wi|Wh] into MFMA B-fragment order, hi/lo split ----------
__global__ void setup_swizzle(const float* __restrict__ Wi, const float* __restrict__ Wh,
                              short* __restrict__ whi, short* __restrict__ wlo) {
    const int idx = blockIdx.x * 256 + threadIdx.x;
    if (idx >= FRAG_TOTAL) return;
    const int l    = idx & 63;
    const int rest = idx >> 6;
    const int t    = rest % 3;
    const int ki   = (rest / 3) % 36;
    const int c    = rest / 108;
    const int nrow = t * 1024 + c * 16 + (l & 15);
    const int kb   = ki * 32 + (l >> 4) * 8;
    short8 vh, vl;
#pragma unroll
    for (int j = 0; j < 8; ++j) {
        const int k = kb + j;
        float w = (k < 128) ? Wi[(size_t)nrow * 128 + k]
                            : Wh[(size_t)nrow * 1024 + (k - 128)];
        short h, lo2;
        f2pair(w, h, lo2);
        vh[j] = h; vl[j] = lo2;
    }
    *(short8*)(whi + (size_t)idx * 8) = vh;
    *(short8*)(wlo + (size_t)idx * 8) = vl;
}

// ---------- main persistent kernel ----------
__global__ __launch_bounds__(512, 2) void gru_main(
    const float* __restrict__ feats, const float* __restrict__ labels,
    const float* __restrict__ bi,    const float* __restrict__ bh,
    const float* __restrict__ Wd,    const float* __restrict__ bd,
    const short* __restrict__ whi_sw, const short* __restrict__ wlo_sw,
    unsigned* __restrict__ h_pack,   float* __restrict__ ps_f32,
    float* __restrict__ out,
    unsigned* __restrict__ bar_cnt, unsigned* __restrict__ bar_gen,
    unsigned* __restrict__ ps_cnt)
{
    __shared__ short s_whi[SLAB_ELEMS];   // 108 KB resident W_hi slab (fragment order)
    __shared__ float s_ps[2048];          // ps-phase h staging (2 rows x 1024)

    const int tid  = threadIdx.x;
    const int lane = tid & 63;
    const int wv   = tid >> 6;            // wave 0..7
    const int q    = lane >> 4;
    const int n16  = lane & 15;
    const int c    = blockIdx.x & 63;     // out-group: h-cols [16c, 16c+16)
    const int r    = blockIdx.x >> 6;     // batch-group: rows [128r, 128r+128)

    // stage W_hi slab
    {
        const f32x4* src = (const f32x4*)(whi_sw + (size_t)c * SLAB_ELEMS);
        f32x4* dst = (f32x4*)s_whi;
        for (int i = tid; i < SLAB_ELEMS / 8; i += 512) dst[i] = src[i];
    }
    __syncthreads();

    const int mbase = r * 128 + wv * 16;  // this wave's 16 batch rows
    const int brow  = mbase + n16;        // A-fragment row for this lane
    const int row_r = c * 16 + n16;       // gate row (within each gate part) == D col
    const float bias_r  = bi[row_r] + bh[row_r];
    const float bias_z  = bi[1024 + row_r] + bh[1024 + row_r];
    const float bias_ni = bi[2048 + row_r];
    const float bias_nh = bh[2048 + row_r];
    const int hcol = row_r;
    const short* wlo_c = wlo_sw + (size_t)c * SLAB_ELEMS;

    unsigned* cnt = bar_cnt + r;
    unsigned* gen = bar_gen + r;
    unsigned* psc = ps_cnt  + r;

    // hoist region-1 W_lo fragments (step-invariant): 12 x short8 = 48 VGPRs
    short8 L0r[4], L1r[4], L2r[4];
#pragma unroll
    for (int ki = 0; ki < 4; ++ki) {
        const int fo = ((ki * 3) * 64 + lane) * 8;
        L0r[ki] = *(const short8*)(wlo_c + fo);
        L1r[ki] = *(const short8*)(wlo_c + fo + 512);
        L2r[ki] = *(const short8*)(wlo_c + fo + 1024);
    }

    float hold[4] = {0.f, 0.f, 0.f, 0.f};  // h carried in-register (lane owns (b,hcol))

    for (int step = 0; step < NSTEPS; ++step) {
        const int  cur = step & 1, nxt = cur ^ 1;
        const bool dec = (step >= SENC);

        floatx4 aR  = (floatx4){bias_r,  bias_r,  bias_r,  bias_r};
        floatx4 aZ  = (floatx4){bias_z,  bias_z,  bias_z,  bias_z};
        floatx4 aNi = (floatx4){bias_ni, bias_ni, bias_ni, bias_ni};
        floatx4 aNh = (floatx4){bias_nh, bias_nh, bias_nh, bias_nh};

        const unsigned* hcur = h_pack + (size_t)cur * HB;

        // ---- region 2 (h part, k 128..1151): h via 8B agent atomics (depth-3),
        // ---- wlo streamed from warm L2 (depth-2) ----
        {
            u64 hq[3][4];
            short8 wl0[2], wl1[2], wl2[2];

            auto ld_h = [&](int ki, u64* dst) {
                const u64* hp = (const u64*)(hcur + (size_t)brow * 1024 + (ki - 4) * 32 + q * 8);
                dst[0] = ldq_dev(hp);     dst[1] = ldq_dev(hp + 1);
                dst[2] = ldq_dev(hp + 2); dst[3] = ldq_dev(hp + 3);
            };
            auto ld_w = [&](int ki, int s) {
                const int fo = ((ki * 3) * 64 + lane) * 8;
                wl0[s] = *(const short8*)(wlo_c + fo);
                wl1[s] = *(const short8*)(wlo_c + fo + 512);
                wl2[s] = *(const short8*)(wlo_c + fo + 1024);
            };

            ld_h(4, hq[0]); ld_h(5, hq[1]); ld_h(6, hq[2]);
            ld_w(4, 0);     ld_w(5, 1);

#pragma unroll
            for (int ki = 4; ki < 36; ++ki) {
                short8 ah, al;
                {
                    u64* hv = hq[(ki - 4) % 3];
#pragma unroll
                    for (int j = 0; j < 4; ++j) {
                        u64 v = hv[j];
                        unsigned p0 = (unsigned)v, p1 = (unsigned)(v >> 32);
                        ah[2 * j]     = (short)(p0 >> 16); al[2 * j]     = (short)p0;
                        ah[2 * j + 1] = (short)(p1 >> 16); al[2 * j + 1] = (short)p1;
                    }
                }
                short8 L0 = wl0[ki & 1], L1 = wl1[ki & 1], L2 = wl2[ki & 1];
                if (ki + 3 < 36) ld_h(ki + 3, hq[(ki - 1) % 3]);
                if (ki + 2 < 36) ld_w(ki + 2, ki & 1);
                const int fo = ((ki * 3) * 64 + lane) * 8;
                short8 b0 = *(const short8*)(s_whi + fo);
                short8 b1 = *(const short8*)(s_whi + fo + 512);
                short8 b2 = *(const short8*)(s_whi + fo + 1024);
                aR  = MFMA(ah, b0, aR);  aR  = MFMA(ah, L0, aR);  aR  = MFMA(al, b0, aR);
                aZ  = MFMA(ah, b1, aZ);  aZ  = MFMA(ah, L1, aZ);  aZ  = MFMA(al, b1, aZ);
                aNh = MFMA(ah, b2, aNh); aNh = MFMA(ah, L2, aNh); aNh = MFMA(al, b2, aNh);
            }
        }

        // ---- ps readiness (decoder): producers ran right after previous rbar;
        // ---- region-2 above gave them ~4us of cover, so this spin is ~free ----
        if (dec) {
            if (tid == 0) {
                const unsigned need = 64u * (unsigned)(step - 127);
                while (ldu_dev(psc) < need) __builtin_amdgcn_s_sleep(1);
            }
            __syncthreads();
        }

        // ---- region 1: x part (k 0..127), fp32 sources, hoisted W_lo ----
#pragma unroll
        for (int ki = 0; ki < 4; ++ki) {
            float f[8];
            if (ki < 2) {
                const float* src = feats + ((size_t)brow * 159 + step) * 64 + ki * 32 + q * 8;
                f32x4 a = ((const f32x4*)src)[0];
                f32x4 b = ((const f32x4*)src)[1];
#pragma unroll
                for (int j = 0; j < 4; ++j) { f[j] = a[j]; f[4 + j] = b[j]; }
            } else if (!dec) {
                const float* src = labels + ((size_t)brow * 128 + step) * 64 + (ki - 2) * 32 + q * 8;
                f32x4 a = ((const f32x4*)src)[0];
                f32x4 b = ((const f32x4*)src)[1];
#pragma unroll
                for (int j = 0; j < 4; ++j) { f[j] = a[j]; f[4 + j] = b[j]; }
            } else {
                const u64* pp = (const u64*)(ps_f32 + (size_t)brow * 64 + (ki - 2) * 32 + q * 8);
#pragma unroll
                for (int j = 0; j < 4; ++j) {
                    u64 v = ldq_dev(pp + j);
                    f[2 * j]     = __uint_as_float((unsigned)v);
                    f[2 * j + 1] = __uint_as_float((unsigned)(v >> 32));
                }
            }
            short8 ah, al;
#pragma unroll
            for (int j = 0; j < 8; ++j) {
                short h2, l2;
                f2pair(f[j], h2, l2);
                ah[j] = h2; al[j] = l2;
            }
            const int fo = ((ki * 3) * 64 + lane) * 8;
            short8 b0 = *(const short8*)(s_whi + fo);
            short8 b1 = *(const short8*)(s_whi + fo + 512);
            short8 b2 = *(const short8*)(s_whi + fo + 1024);
            aR  = MFMA(ah, b0, aR);  aR  = MFMA(ah, L0r[ki], aR);  aR  = MFMA(al, b0, aR);
            aZ  = MFMA(ah, b1, aZ);  aZ  = MFMA(ah, L1r[ki], aZ);  aZ  = MFMA(al, b1, aZ);
            aNi = MFMA(ah, b2, aNi); aNi = MFMA(ah, L2r[ki], aNi); aNi = MFMA(al, b2, aNi);
        }

        // ---- epilogue: GRU update, h carried in regs, packed atomic stores ----
        {
            unsigned* nh = h_pack + (size_t)nxt * HB;
#pragma unroll
            for (int i = 0; i < 4; ++i) {
                const int b = mbase + q * 4 + i;     // D row = (lane>>4)*4 + reg
                float rr = sigm(aR[i]);
                float zz = sigm(aZ[i]);
                float nn = tanh_fast(aNi[i] + rr * aNh[i]);
                float hv = (1.0f - zz) * nn + zz * hold[i];
                hold[i] = hv;
                short sh, sl;
                f2pair(hv, sh, sl);
                unsigned pk = ((unsigned)(unsigned short)sh << 16) | (unsigned)(unsigned short)sl;
                stu_dev(nh + (size_t)b * 1024 + hcol, pk);
            }
        }
        rbar(cnt, gen, (unsigned)step);   // publish h within r-group (no cache fences)

        // ---- ps phase: after encoder (step 127) and every decoder step ----
        if (step >= SENC - 1) {
            const int ot = step - (SENC - 1);        // output time 0..31
            const unsigned* hnew = h_pack + (size_t)((step + 1) & 1) * HB;
            const int prow0 = r * 128 + 2 * c;       // this block's 2 ps rows
            // stage 2 h rows into LDS (atomic reads, unpack hi+lo -> f32)
#pragma unroll
            for (int i = tid; i < 2048; i += 512) {
                const int rr2 = i >> 10, k = i & 1023;
                unsigned pv = ldu_dev(hnew + (size_t)(prow0 + rr2) * 1024 + k);
                s_ps[i] = __uint_as_float(pv & 0xFFFF0000u) + __uint_as_float(pv << 16);
            }
            __syncthreads();
            const int dot = tid >> 2, quar = tid & 3;
            const int rr2 = dot >> 6, o = dot & 63;
            const float* wrow = Wd + (size_t)o * 1024 + quar * 256;
            const float* hrow = s_ps + rr2 * 1024 + quar * 256;
            float acc = 0.0f;
#pragma unroll 8
            for (int k = 0; k < 256; k += 4) {
                f32x4 w = *(const f32x4*)(wrow + k);
                acc += hrow[k] * w[0] + hrow[k + 1] * w[1]
                     + hrow[k + 2] * w[2] + hrow[k + 3] * w[3];
            }
            acc += __shfl_xor(acc, 1);
            acc += __shfl_xor(acc, 2);
            if (quar == 0) {
                float v = acc + bd[o];
                out[((size_t)ot * 512 + prow0 + rr2) * 64 + o] = v;
                stf_dev(ps_f32 + (size_t)(prow0 + rr2) * 64 + o, v);
            }
            asm volatile("s_waitcnt vmcnt(0)" ::: "memory");
            __syncthreads();
            if (tid == 0)
                __hip_atomic_fetch_add(psc, 1u, __ATOMIC_RELAXED, __HIP_MEMORY_SCOPE_AGENT);
            __syncthreads();
        }
    }
}

extern "C" void kernel_launch(void* const* d_in, const int* in_sizes, int n_in,
                              void* d_out, int out_size, void* d_ws, size_t ws_size,
                              hipStream_t stream) {
    const float* feats  = (const float*)d_in[0];
    const float* labels = (const float*)d_in[1];
    const float* Wi     = (const float*)d_in[2];
    const float* Wh     = (const float*)d_in[3];
    const float* bi     = (const float*)d_in[4];
    const float* bh     = (const float*)d_in[5];
    const float* Wd     = (const float*)d_in[6];
    const float* bd     = (const float*)d_in[7];
    float* out = (float*)d_out;

    char* ws = (char*)d_ws;
    short*    whi_sw  = (short*)(ws);                  // 7,077,888 B
    short*    wlo_sw  = (short*)(ws + 7077888);        // 7,077,888 B
    unsigned* h_pack  = (unsigned*)(ws + 14155776);    // 4,194,304 B (2 buffers, hi|lo packed)
    float*    ps_f32  = (float*)(ws + 18350080);       //   131,072 B
    unsigned* bar_cnt = (unsigned*)(ws + 18481152);    //        16 B (4 r-groups)
    unsigned* bar_gen = (unsigned*)(ws + 18481168);    //        16 B
    unsigned* ps_cnt  = (unsigned*)(ws + 18481184);    //        16 B

    // zero h buffer 0 (buffer 1 is written before first read) and sync state
    hipMemsetAsync(h_pack, 0, 2097152, stream);
    hipMemsetAsync(bar_cnt, 0, 48, stream);

    setup_swizzle<<<FRAG_TOTAL / 256, 256, 0, stream>>>(Wi, Wh, whi_sw, wlo_sw);

    void* args[] = {(void*)&feats, (void*)&labels, (void*)&bi, (void*)&bh,
                    (void*)&Wd, (void*)&bd, (void*)&whi_sw, (void*)&wlo_sw,
                    (void*)&h_pack, (void*)&ps_f32, (void*)&out,
                    (void*)&bar_cnt, (void*)&bar_gen, (void*)&ps_cnt};
    hipLaunchCooperativeKernel(reinterpret_cast<void*>(gru_main),
                               dim3(256), dim3(512), args, 0, stream);
}

// Round 4
// 5990.594 us; speedup vs baseline: 2.0149x; 2.0149x over previous
//
#include <hip/hip_runtime.h>
#include <cstdint>
#include <cstddef>

// Problem constants
#define SENC  128
#define NSTEPS 159          // 128 encoder + 31 decoder
#define HB16  524288        // elements (shorts) per h buffer (512*1024)
#define SLAB_ELEMS 55296    // per-c weight slab: 36*3*64*8 shorts
#define FRAG_TOTAL 442368   // 64*36*3*64 fragment slots

typedef short  short8  __attribute__((ext_vector_type(8)));
typedef float  floatx4 __attribute__((ext_vector_type(4)));
typedef float  f32x4   __attribute__((ext_vector_type(4)));
typedef int    i32x4   __attribute__((ext_vector_type(4)));
typedef unsigned long long u64;

#define MFMA(a, b, c) __builtin_amdgcn_mfma_f32_16x16x32_bf16((a), (b), (c), 0, 0, 0)

// ---------- raw asm loads: nc = coherent-uncached (bypass L1/L2, sc0 sc1),
// ---------- c = normal cached. 16B each. memory clobber pins program order.
__device__ __forceinline__ i32x4 ld_nc16(const void* p) {
    i32x4 r;
    asm volatile("global_load_dwordx4 %0, %1, off sc0 sc1"
                 : "=&v"(r) : "v"(p) : "memory");
    return r;
}
__device__ __forceinline__ i32x4 ld_c16(const void* p) {
    i32x4 r;
    asm volatile("global_load_dwordx4 %0, %1, off"
                 : "=&v"(r) : "v"(p) : "memory");
    return r;
}
__device__ __forceinline__ void st_nc16(short* p, unsigned v) {
    asm volatile("global_store_short %0, %1, off sc0 sc1"
                 :: "v"(p), "v"(v) : "memory");
}
#define WAITVM(N) asm volatile("s_waitcnt vmcnt(" #N ")" ::: "memory")

// ---------- agent-scope relaxed atomics (coherent, bypass L1/L2) ----------
__device__ __forceinline__ unsigned ldu_dev(const unsigned* p) {
    return __hip_atomic_load(p, __ATOMIC_RELAXED, __HIP_MEMORY_SCOPE_AGENT);
}
__device__ __forceinline__ u64 ldq_dev(const u64* p) {
    return __hip_atomic_load(p, __ATOMIC_RELAXED, __HIP_MEMORY_SCOPE_AGENT);
}
__device__ __forceinline__ void stu_dev(unsigned* p, unsigned v) {
    __hip_atomic_store(p, v, __ATOMIC_RELAXED, __HIP_MEMORY_SCOPE_AGENT);
}
__device__ __forceinline__ void stf_dev(float* p, float v) {
    __hip_atomic_store(p, v, __ATOMIC_RELAXED, __HIP_MEMORY_SCOPE_AGENT);
}

// ---------- bf16 helpers (RNE) ----------
__device__ __forceinline__ float bf2f(short s) {
    return __uint_as_float(((unsigned)(unsigned short)s) << 16);
}
__device__ __forceinline__ short f2bf(float f) {
    unsigned u = __float_as_uint(f);
    return (short)((u + 0x7FFFu + ((u >> 16) & 1u)) >> 16);
}
__device__ __forceinline__ void f2pair(float f, short& hi, short& lo) {
    hi = f2bf(f);
    lo = f2bf(f - bf2f(hi));
}

__device__ __forceinline__ float sigm(float x) {
    return 1.0f / (1.0f + __expf(-x));
}
__device__ __forceinline__ float tanh_fast(float x) {
    float cx = fminf(fmaxf(x, -15.0f), 15.0f);
    float e = __expf(2.0f * cx);
    return (e - 1.0f) / (e + 1.0f);
}

// ---------- fence-free r-group barrier (64 blocks) ----------
__device__ __forceinline__ void rbar(unsigned* cnt, unsigned* gen, unsigned epoch) {
    WAITVM(0);
    __syncthreads();
    if (threadIdx.x == 0) {
        unsigned old = __hip_atomic_fetch_add(cnt, 1u, __ATOMIC_RELAXED, __HIP_MEMORY_SCOPE_AGENT);
        if (old == epoch * 64u + 63u) {
            stu_dev(gen, epoch + 1u);
        } else {
            while (ldu_dev(gen) <= epoch) __builtin_amdgcn_s_sleep(1);
        }
    }
    __syncthreads();
}

// ---------- setup: swizzle [Wi|Wh] into MFMA B-fragment order, hi/lo split ----------
__global__ void setup_swizzle(const float* __restrict__ Wi, const float* __restrict__ Wh,
                              short* __restrict__ whi, short* __restrict__ wlo) {
    const int idx = blockIdx.x * 256 + threadIdx.x;
    if (idx >= FRAG_TOTAL) return;
    const int l    = idx & 63;
    const int rest = idx >> 6;
    const int t    = rest % 3;
    const int ki   = (rest / 3) % 36;
    const int c    = rest / 108;
    const int nrow = t * 1024 + c * 16 + (l & 15);
    const int kb   = ki * 32 + (l >> 4) * 8;
    short8 vh, vl;
#pragma unroll
    for (int j = 0; j < 8; ++j) {
        const int k = kb + j;
        float w = (k < 128) ? Wi[(size_t)nrow * 128 + k]
                            : Wh[(size_t)nrow * 1024 + (k - 128)];
        short h, lo2;
        f2pair(w, h, lo2);
        vh[j] = h; vl[j] = lo2;
    }
    *(short8*)(whi + (size_t)idx * 8) = vh;
    *(short8*)(wlo + (size_t)idx * 8) = vl;
}

// ---------- main persistent kernel ----------
__global__ __launch_bounds__(512, 2) void gru_main(
    const float* __restrict__ feats, const float* __restrict__ labels,
    const float* __restrict__ bi,    const float* __restrict__ bh,
    const float* __restrict__ Wd,    const float* __restrict__ bd,
    const short* __restrict__ whi_sw, const short* __restrict__ wlo_sw,
    short* __restrict__ h16,         float* __restrict__ ps_f32,
    float* __restrict__ out,
    unsigned* __restrict__ bar_cnt, unsigned* __restrict__ bar_gen,
    unsigned* __restrict__ ps_cnt)
{
    __shared__ short s_whi[SLAB_ELEMS];   // 108 KB resident W_hi slab (fragment order)
    __shared__ float s_ps[2048];          // ps-phase h staging (2 rows x 1024)

    const int tid  = threadIdx.x;
    const int lane = tid & 63;
    const int wv   = tid >> 6;            // wave 0..7
    const int q    = lane >> 4;
    const int n16  = lane & 15;
    const int c    = blockIdx.x & 63;     // out-group: h-cols [16c, 16c+16)
    const int r    = blockIdx.x >> 6;     // batch-group: rows [128r, 128r+128)

    // stage W_hi slab
    {
        const f32x4* src = (const f32x4*)(whi_sw + (size_t)c * SLAB_ELEMS);
        f32x4* dst = (f32x4*)s_whi;
        for (int i = tid; i < SLAB_ELEMS / 8; i += 512) dst[i] = src[i];
    }
    __syncthreads();

    const int mbase = r * 128 + wv * 16;  // this wave's 16 batch rows
    const int brow  = mbase + n16;        // A-fragment row for this lane
    const int row_r = c * 16 + n16;       // gate row (within each gate part) == D col
    const float bias_r  = bi[row_r] + bh[row_r];
    const float bias_z  = bi[1024 + row_r] + bh[1024 + row_r];
    const float bias_ni = bi[2048 + row_r];
    const float bias_nh = bh[2048 + row_r];
    const int hcol = row_r;
    const short* wlo_c = wlo_sw + (size_t)c * SLAB_ELEMS;

    unsigned* cnt = bar_cnt + r;
    unsigned* gen = bar_gen + r;
    unsigned* psc = ps_cnt  + r;

    float hold[4] = {0.f, 0.f, 0.f, 0.f};  // h carried fp32 in-register (lane owns (b,hcol))

    for (int step = 0; step < NSTEPS; ++step) {
        const int  cur = step & 1, nxt = cur ^ 1;
        const bool dec = (step >= SENC);

        floatx4 aR  = (floatx4){bias_r,  bias_r,  bias_r,  bias_r};
        floatx4 aZ  = (floatx4){bias_z,  bias_z,  bias_z,  bias_z};
        floatx4 aNi = (floatx4){bias_ni, bias_ni, bias_ni, bias_ni};
        floatx4 aNh = (floatx4){bias_nh, bias_nh, bias_nh, bias_nh};

        // ---- region 2 (h part, k 128..1151): hi-only h via one dwordx4 sc0sc1
        // ---- per lane per ki; W_lo cached; depth-4 manual vmcnt pipeline ----
        {
            const short* hrow = h16 + (size_t)cur * HB16 + (size_t)brow * 1024 + q * 8;
            i32x4 hb[4], w0[4], w1[4], w2[4];

#define ISSUE(S, KI) do { \
    hb[S] = ld_nc16(hrow + (size_t)((KI) - 4) * 32); \
    const short* wp_ = wlo_c + (size_t)(KI) * 1536 + lane * 8; \
    w0[S] = ld_c16(wp_); w1[S] = ld_c16(wp_ + 512); w2[S] = ld_c16(wp_ + 1024); \
} while (0)

#define CONSUME(S, KI) do { \
    short8 ah  = *(short8*)&hb[S]; \
    short8 Bl0 = *(short8*)&w0[S]; \
    short8 Bl1 = *(short8*)&w1[S]; \
    short8 Bl2 = *(short8*)&w2[S]; \
    const int fo_ = (((KI) * 3) * 64 + lane) * 8; \
    short8 b0 = *(const short8*)(s_whi + fo_); \
    short8 b1 = *(const short8*)(s_whi + fo_ + 512); \
    short8 b2 = *(const short8*)(s_whi + fo_ + 1024); \
    aR  = MFMA(ah, b0, aR);  aR  = MFMA(ah, Bl0, aR); \
    aZ  = MFMA(ah, b1, aZ);  aZ  = MFMA(ah, Bl1, aZ); \
    aNh = MFMA(ah, b2, aNh); aNh = MFMA(ah, Bl2, aNh); \
} while (0)

            ISSUE(0, 4); ISSUE(1, 5); ISSUE(2, 6); ISSUE(3, 7);
#pragma unroll
            for (int ki = 4; ki < 33; ++ki) {
                WAITVM(12);
                const int s = (ki - 4) & 3;
                switch (s) {
                    case 0: CONSUME(0, ki); if (ki + 4 < 36) ISSUE(0, ki + 4); break;
                    case 1: CONSUME(1, ki); if (ki + 4 < 36) ISSUE(1, ki + 4); break;
                    case 2: CONSUME(2, ki); if (ki + 4 < 36) ISSUE(2, ki + 4); break;
                    case 3: CONSUME(3, ki); if (ki + 4 < 36) ISSUE(3, ki + 4); break;
                }
            }
            WAITVM(8);  CONSUME(1, 33);
            WAITVM(4);  CONSUME(2, 34);
            WAITVM(0);  CONSUME(3, 35);
#undef ISSUE
#undef CONSUME
        }

        // ---- ps readiness (decoder): region-2 above covered the producers ----
        if (dec) {
            if (tid == 0) {
                const unsigned need = 64u * (unsigned)(step - 127);
                while (ldu_dev(psc) < need) __builtin_amdgcn_s_sleep(1);
            }
            __syncthreads();
        }

        // ---- region 1: x part (k 0..127), fp32 sources, 3-term, cached W_lo ----
#pragma unroll
        for (int ki = 0; ki < 4; ++ki) {
            float f[8];
            if (ki < 2) {
                const float* src = feats + ((size_t)brow * 159 + step) * 64 + ki * 32 + q * 8;
                f32x4 a = ((const f32x4*)src)[0];
                f32x4 b = ((const f32x4*)src)[1];
#pragma unroll
                for (int j = 0; j < 4; ++j) { f[j] = a[j]; f[4 + j] = b[j]; }
            } else if (!dec) {
                const float* src = labels + ((size_t)brow * 128 + step) * 64 + (ki - 2) * 32 + q * 8;
                f32x4 a = ((const f32x4*)src)[0];
                f32x4 b = ((const f32x4*)src)[1];
#pragma unroll
                for (int j = 0; j < 4; ++j) { f[j] = a[j]; f[4 + j] = b[j]; }
            } else {
                const u64* pp = (const u64*)(ps_f32 + (size_t)brow * 64 + (ki - 2) * 32 + q * 8);
#pragma unroll
                for (int j = 0; j < 4; ++j) {
                    u64 v = ldq_dev(pp + j);
                    f[2 * j]     = __uint_as_float((unsigned)v);
                    f[2 * j + 1] = __uint_as_float((unsigned)(v >> 32));
                }
            }
            short8 ah, al;
#pragma unroll
            for (int j = 0; j < 8; ++j) {
                short h2, l2;
                f2pair(f[j], h2, l2);
                ah[j] = h2; al[j] = l2;
            }
            const int fo = ((ki * 3) * 64 + lane) * 8;
            short8 b0 = *(const short8*)(s_whi + fo);
            short8 b1 = *(const short8*)(s_whi + fo + 512);
            short8 b2 = *(const short8*)(s_whi + fo + 1024);
            short8 l0 = *(const short8*)(wlo_c + fo);
            short8 l1 = *(const short8*)(wlo_c + fo + 512);
            short8 l2v = *(const short8*)(wlo_c + fo + 1024);
            aR  = MFMA(ah, b0, aR);  aR  = MFMA(ah, l0, aR);   aR  = MFMA(al, b0, aR);
            aZ  = MFMA(ah, b1, aZ);  aZ  = MFMA(ah, l1, aZ);   aZ  = MFMA(al, b1, aZ);
            aNi = MFMA(ah, b2, aNi); aNi = MFMA(ah, l2v, aNi); aNi = MFMA(al, b2, aNi);
        }

        // ---- epilogue: GRU update, fp32 hold in regs, bf16-hi exchange stores ----
        {
            short* nh = h16 + (size_t)nxt * HB16;
#pragma unroll
            for (int i = 0; i < 4; ++i) {
                const int b = mbase + q * 4 + i;     // D row = (lane>>4)*4 + reg
                float rr = sigm(aR[i]);
                float zz = sigm(aZ[i]);
                float nn = tanh_fast(aNi[i] + rr * aNh[i]);
                float hv = (1.0f - zz) * nn + zz * hold[i];
                hold[i] = hv;
                st_nc16(nh + (size_t)b * 1024 + hcol,
                        (unsigned)(unsigned short)f2bf(hv));
            }
        }
        rbar(cnt, gen, (unsigned)step);   // publish h within r-group

        // ---- ps phase: after encoder (step 127) and every decoder step ----
        if (step >= SENC - 1) {
            const int ot = step - (SENC - 1);        // output time 0..31
            const short* hnew = h16 + (size_t)((step + 1) & 1) * HB16;
            const int prow0 = r * 128 + 2 * c;       // this block's 2 ps rows
            // stage 2 h rows into LDS (uncoherent dword loads, bf16 -> f32)
            {
                const unsigned* hsrc = (const unsigned*)(hnew + (size_t)prow0 * 1024);
                unsigned pv0 = ldu_dev(hsrc + tid);
                unsigned pv1 = ldu_dev(hsrc + 512 + tid);
                s_ps[2 * tid]        = __uint_as_float(pv0 << 16);
                s_ps[2 * tid + 1]    = __uint_as_float(pv0 & 0xFFFF0000u);
                s_ps[1024 + 2 * tid] = __uint_as_float(pv1 << 16);
                s_ps[1025 + 2 * tid] = __uint_as_float(pv1 & 0xFFFF0000u);
            }
            __syncthreads();
            const int dot = tid >> 2, quar = tid & 3;
            const int rr2 = dot >> 6, o = dot & 63;
            const float* wrow = Wd + (size_t)o * 1024;
            const float* hrow = s_ps + rr2 * 1024;
            float acc = 0.0f;
#pragma unroll 8
            for (int j = 0; j < 64; ++j) {           // interleaved K-slices: conflict-free
                const int k = j * 16 + quar * 4;
                f32x4 w = *(const f32x4*)(wrow + k);
                f32x4 h4 = *(const f32x4*)(hrow + k);
                acc += h4[0] * w[0] + h4[1] * w[1] + h4[2] * w[2] + h4[3] * w[3];
            }
            acc += __shfl_xor(acc, 1);
            acc += __shfl_xor(acc, 2);
            if (quar == 0) {
                float v = acc + bd[o];
                out[((size_t)ot * 512 + prow0 + rr2) * 64 + o] = v;
                stf_dev(ps_f32 + (size_t)(prow0 + rr2) * 64 + o, v);
            }
            WAITVM(0);
            __syncthreads();
            if (tid == 0)
                __hip_atomic_fetch_add(psc, 1u, __ATOMIC_RELAXED, __HIP_MEMORY_SCOPE_AGENT);
            __syncthreads();
        }
    }
}

extern "C" void kernel_launch(void* const* d_in, const int* in_sizes, int n_in,
                              void* d_out, int out_size, void* d_ws, size_t ws_size,
                              hipStream_t stream) {
    const float* feats  = (const float*)d_in[0];
    const float* labels = (const float*)d_in[1];
    const float* Wi     = (const float*)d_in[2];
    const float* Wh     = (const float*)d_in[3];
    const float* bi     = (const float*)d_in[4];
    const float* bh     = (const float*)d_in[5];
    const float* Wd     = (const float*)d_in[6];
    const float* bd     = (const float*)d_in[7];
    float* out = (float*)d_out;

    char* ws = (char*)d_ws;
    short*    whi_sw  = (short*)(ws);                  // 7,077,888 B
    short*    wlo_sw  = (short*)(ws + 7077888);        // 7,077,888 B
    short*    h16     = (short*)(ws + 14155776);       // 2,097,152 B (2 buffers, bf16-hi)
    float*    ps_f32  = (float*)(ws + 16252928);       //   131,072 B
    unsigned* bar_cnt = (unsigned*)(ws + 16384000);    //        16 B (4 r-groups)
    unsigned* bar_gen = (unsigned*)(ws + 16384016);    //        16 B
    unsigned* ps_cnt  = (unsigned*)(ws + 16384032);    //        16 B

    // zero h buffer 0 (buffer 1 is written before first read) and sync state
    hipMemsetAsync(h16, 0, 1048576, stream);
    hipMemsetAsync(bar_cnt, 0, 48, stream);

    setup_swizzle<<<FRAG_TOTAL / 256, 256, 0, stream>>>(Wi, Wh, whi_sw, wlo_sw);

    void* args[] = {(void*)&feats, (void*)&labels, (void*)&bi, (void*)&bh,
                    (void*)&Wd, (void*)&bd, (void*)&whi_sw, (void*)&wlo_sw,
                    (void*)&h16, (void*)&ps_f32, (void*)&out,
                    (void*)&bar_cnt, (void*)&bar_gen, (void*)&ps_cnt};
    hipLaunchCooperativeKernel(reinterpret_cast<void*>(gru_main),
                               dim3(256), dim3(512), args, 0, stream);
}

// Round 5
// 4266.922 us; speedup vs baseline: 2.8289x; 1.4040x over previous
//
#include <hip/hip_runtime.h>
#include <cstdint>
#include <cstddef>

// Problem constants
#define SENC  128
#define NSTEPS 159          // 128 encoder + 31 decoder
#define HB16  524288        // shorts per h buffer (512*1024)
#define XSLICE 131072       // shorts per (xcd,r) slice: 128*1024
#define SLAB_ELEMS 55296    // per-c W_hi slab: 36*3*64*8 shorts
#define FRAG_TOTAL 442368   // 64*36*3*64 fragment slots

typedef short  short8  __attribute__((ext_vector_type(8)));
typedef float  floatx4 __attribute__((ext_vector_type(4)));
typedef float  f32x4   __attribute__((ext_vector_type(4)));
typedef int    i32x4   __attribute__((ext_vector_type(4)));
typedef unsigned long long u64;

#define MFMA(a, b, c) __builtin_amdgcn_mfma_f32_16x16x32_bf16((a), (b), (c), 0, 0, 0)

// ---------- raw asm memory ops (memory clobber pins program order) ----------
__device__ __forceinline__ i32x4 ld_nc16(const void* p) {      // bypass L1+L2 (coherence point)
    i32x4 r;
    asm volatile("global_load_dwordx4 %0, %1, off sc0 sc1" : "=&v"(r) : "v"(p) : "memory");
    return r;
}
__device__ __forceinline__ i32x4 ld_sc0_16(const void* p) {    // bypass L1, hit local L2
    i32x4 r;
    asm volatile("global_load_dwordx4 %0, %1, off sc0" : "=&v"(r) : "v"(p) : "memory");
    return r;
}
__device__ __forceinline__ void st_c16(void* p, i32x4 v) {     // plain cached store (own L2)
    asm volatile("global_store_dwordx4 %0, %1, off" :: "v"(p), "v"(v) : "memory");
}
__device__ __forceinline__ void st_nc16(short* p, unsigned v) { // uncoherent 2B store
    asm volatile("global_store_short %0, %1, off sc0 sc1" :: "v"(p), "v"(v) : "memory");
}
#define WAITVM(N) asm volatile("s_waitcnt vmcnt(" #N ")" ::: "memory")

__device__ __forceinline__ int xcc_id() {
    unsigned v;
    asm volatile("s_getreg_b32 %0, hwreg(HW_REG_XCC_ID)" : "=s"(v));
    return (int)(v & 7);
}

// ---------- agent-scope relaxed atomics ----------
__device__ __forceinline__ unsigned ldu_dev(const unsigned* p) {
    return __hip_atomic_load(p, __ATOMIC_RELAXED, __HIP_MEMORY_SCOPE_AGENT);
}
__device__ __forceinline__ u64 ldq_dev(const u64* p) {
    return __hip_atomic_load(p, __ATOMIC_RELAXED, __HIP_MEMORY_SCOPE_AGENT);
}
__device__ __forceinline__ void stu_dev(unsigned* p, unsigned v) {
    __hip_atomic_store(p, v, __ATOMIC_RELAXED, __HIP_MEMORY_SCOPE_AGENT);
}
__device__ __forceinline__ void stf_dev(float* p, float v) {
    __hip_atomic_store(p, v, __ATOMIC_RELAXED, __HIP_MEMORY_SCOPE_AGENT);
}
__device__ __forceinline__ unsigned addu_dev(unsigned* p, unsigned v) {
    return __hip_atomic_fetch_add(p, v, __ATOMIC_RELAXED, __HIP_MEMORY_SCOPE_AGENT);
}

// ---------- bf16 helpers (RNE) ----------
__device__ __forceinline__ float bf2f(short s) {
    return __uint_as_float(((unsigned)(unsigned short)s) << 16);
}
__device__ __forceinline__ short f2bf(float f) {
    unsigned u = __float_as_uint(f);
    return (short)((u + 0x7FFFu + ((u >> 16) & 1u)) >> 16);
}
__device__ __forceinline__ void f2pair(float f, short& hi, short& lo) {
    hi = f2bf(f);
    lo = f2bf(f - bf2f(hi));
}

__device__ __forceinline__ float sigm(float x) {
    return 1.0f / (1.0f + __expf(-x));
}
__device__ __forceinline__ float tanh_fast(float x) {
    float cx = fminf(fmaxf(x, -15.0f), 15.0f);
    float e = __expf(2.0f * cx);
    return (e - 1.0f) / (e + 1.0f);
}

// ---------- fence-free r-group barrier (64 blocks) ----------
__device__ __forceinline__ void rbar(unsigned* cnt, unsigned* gen, unsigned epoch) {
    WAITVM(0);
    __syncthreads();
    if (threadIdx.x == 0) {
        unsigned old = addu_dev(cnt, 1u);
        if (old == epoch * 64u + 63u) {
            stu_dev(gen, epoch + 1u);
        } else {
            while (ldu_dev(gen) <= epoch) __builtin_amdgcn_s_sleep(1);
        }
    }
    __syncthreads();
}

// ---------- setup: swizzle W_hi (all K) + Wi_lo (x-part only) into fragment order ----------
__global__ void setup_swizzle(const float* __restrict__ Wi, const float* __restrict__ Wh,
                              short* __restrict__ whi, short* __restrict__ wlo_x) {
    const int idx = blockIdx.x * 256 + threadIdx.x;
    if (idx >= FRAG_TOTAL) return;
    const int l    = idx & 63;
    const int rest = idx >> 6;
    const int t    = rest % 3;
    const int ki   = (rest / 3) % 36;
    const int c    = rest / 108;
    const int nrow = t * 1024 + c * 16 + (l & 15);
    const int kb   = ki * 32 + (l >> 4) * 8;
    short8 vh, vl;
#pragma unroll
    for (int j = 0; j < 8; ++j) {
        const int k = kb + j;
        float w = (k < 128) ? Wi[(size_t)nrow * 128 + k]
                            : Wh[(size_t)nrow * 1024 + (k - 128)];
        short h, lo2;
        f2pair(w, h, lo2);
        vh[j] = h; vl[j] = lo2;
    }
    *(short8*)(whi + (size_t)idx * 8) = vh;
    if (ki < 4) {   // x-part W_lo kept (register-hoisted in main kernel)
        const int xi = ((c * 4 + ki) * 3 + t) * 64 + l;
        *(short8*)(wlo_x + (size_t)xi * 8) = vl;
    }
}

// ---------- main persistent kernel ----------
__global__ __launch_bounds__(512, 2) void gru_main(
    const float* __restrict__ feats, const float* __restrict__ labels,
    const float* __restrict__ bi,    const float* __restrict__ bh,
    const float* __restrict__ Wd,    const float* __restrict__ bd,
    const short* __restrict__ whi_sw, const short* __restrict__ wlo_x,
    short* __restrict__ h16,         short* __restrict__ xbuf,
    float* __restrict__ ps_f32,      float* __restrict__ out,
    unsigned* __restrict__ ctrl)
{
    // ctrl layout: [0..3] bar_cnt, [4..7] bar_gen, [8..11] ps_cnt,
    //              [12..43] xreg (8x4), [44..75] xcnt (8x4), [76] gcnt, [77] ggen
    __shared__ short s_whi[SLAB_ELEMS];   // 108 KB resident W_hi slab (fragment order)
    __shared__ float s_ps[2048];          // ps-phase h staging (2 rows x 1024)
    __shared__ int s_x, s_myidx, s_g;

    const int tid  = threadIdx.x;
    const int lane = tid & 63;
    const int wv   = tid >> 6;            // wave 0..7
    const int q    = lane >> 4;
    const int n16  = lane & 15;
    const int c    = blockIdx.x & 63;     // out-group: h-cols [16c, 16c+16)
    const int r    = blockIdx.x >> 6;     // batch-group: rows [128r, 128r+128)

    // ---- registration: dynamic (XCD, r) octet membership + one-shot grid gate ----
    if (tid == 0) {
        const int x = xcc_id();
        s_x = x;
        s_myidx = (int)addu_dev(ctrl + 12 + x * 4 + r, 1u);
        unsigned o = addu_dev(ctrl + 76, 1u);
        if (o == 255u) stu_dev(ctrl + 77, 1u);
        else while (ldu_dev(ctrl + 77) < 1u) __builtin_amdgcn_s_sleep(1);
        s_g = (int)ldu_dev(ctrl + 12 + x * 4 + r);
    }

    // stage W_hi slab while registration settles
    {
        const f32x4* src = (const f32x4*)(whi_sw + (size_t)c * SLAB_ELEMS);
        f32x4* dst = (f32x4*)s_whi;
        for (int i = tid; i < SLAB_ELEMS / 8; i += 512) dst[i] = src[i];
    }
    __syncthreads();

    const int myx = s_x, myidx = s_myidx, g = s_g;
    const int mbase = r * 128 + wv * 16;  // this wave's 16 batch rows
    const int brow  = mbase + n16;        // A-fragment row for this lane
    const int row_r = c * 16 + n16;       // gate row == D col
    const float bias_r  = bi[row_r] + bh[row_r];
    const float bias_z  = bi[1024 + row_r] + bh[1024 + row_r];
    const float bias_ni = bi[2048 + row_r];
    const float bias_nh = bh[2048 + row_r];
    const int hcol = row_r;

    unsigned* bcnt = ctrl + r;
    unsigned* bgen = ctrl + 4 + r;
    unsigned* psc  = ctrl + 8 + r;
    unsigned* xcnt = ctrl + 44 + myx * 4 + r;

    // hoist region-1 W_lo fragments (step-invariant): 12 x short8 = 48 VGPRs
    short8 L0r[4], L1r[4], L2r[4];
#pragma unroll
    for (int ki = 0; ki < 4; ++ki) {
        const short* base = wlo_x + (size_t)(((c * 4 + ki) * 3) * 64 + lane) * 8;
        L0r[ki] = *(const short8*)(base);
        L1r[ki] = *(const short8*)(base + 512);
        L2r[ki] = *(const short8*)(base + 1024);
    }

    const short* xslice = xbuf + (size_t)(myx * 4 + r) * XSLICE;   // local-XCD replica
    const short* hrow0  = xslice + (size_t)(wv * 16 + n16) * 1024 + q * 8;

    float hold[4] = {0.f, 0.f, 0.f, 0.f};  // h carried fp32 in-register

    for (int step = 0; step < NSTEPS; ++step) {
        const int  nxt = (step & 1) ^ 1;
        const bool dec = (step >= SENC);

        floatx4 aR  = (floatx4){bias_r,  bias_r,  bias_r,  bias_r};
        floatx4 aZ  = (floatx4){bias_z,  bias_z,  bias_z,  bias_z};
        floatx4 aNi = (floatx4){bias_ni, bias_ni, bias_ni, bias_ni};
        floatx4 aNh = (floatx4){bias_nh, bias_nh, bias_nh, bias_nh};

        // ---- octet-wait: stage(step-1) complete -> xbuf holds h(step) ----
        if (step > 0) {
            if (tid == 0) {
                const unsigned need = (unsigned)(g * step);
                while (ldu_dev(xcnt) < need) __builtin_amdgcn_s_sleep(1);
            }
            __syncthreads();

            // ---- region 2 (h part): local-L2 sc0 reads, depth-8 pipeline, 3 MFMA/ki ----
            i32x4 hb[8];
#define HISSUE(S, KI) hb[S] = ld_sc0_16(hrow0 + ((KI) - 4) * 32)
#define HCONS(S, KI) do { \
    short8 ah = *(short8*)&hb[S]; \
    const int fo_ = (((KI) * 3) * 64 + lane) * 8; \
    short8 b0 = *(const short8*)(s_whi + fo_); \
    short8 b1 = *(const short8*)(s_whi + fo_ + 512); \
    short8 b2 = *(const short8*)(s_whi + fo_ + 1024); \
    aR  = MFMA(ah, b0, aR); \
    aZ  = MFMA(ah, b1, aZ); \
    aNh = MFMA(ah, b2, aNh); \
} while (0)
            HISSUE(0, 4);  HISSUE(1, 5);  HISSUE(2, 6);  HISSUE(3, 7);
            HISSUE(4, 8);  HISSUE(5, 9);  HISSUE(6, 10); HISSUE(7, 11);
#pragma unroll
            for (int kb = 4; kb < 28; kb += 8) {
                WAITVM(7); HCONS(0, kb + 0); HISSUE(0, kb + 8);
                WAITVM(7); HCONS(1, kb + 1); HISSUE(1, kb + 9);
                WAITVM(7); HCONS(2, kb + 2); HISSUE(2, kb + 10);
                WAITVM(7); HCONS(3, kb + 3); HISSUE(3, kb + 11);
                WAITVM(7); HCONS(4, kb + 4); HISSUE(4, kb + 12);
                WAITVM(7); HCONS(5, kb + 5); HISSUE(5, kb + 13);
                WAITVM(7); HCONS(6, kb + 6); HISSUE(6, kb + 14);
                WAITVM(7); HCONS(7, kb + 7); HISSUE(7, kb + 15);
            }
            WAITVM(7); HCONS(0, 28);
            WAITVM(6); HCONS(1, 29);
            WAITVM(5); HCONS(2, 30);
            WAITVM(4); HCONS(3, 31);
            WAITVM(3); HCONS(4, 32);
            WAITVM(2); HCONS(5, 33);
            WAITVM(1); HCONS(6, 34);
            WAITVM(0); HCONS(7, 35);
#undef HISSUE
#undef HCONS
        }

        // ---- ps readiness (decoder) ----
        if (dec) {
            if (tid == 0) {
                const unsigned need = 64u * (unsigned)(step - 127);
                while (ldu_dev(psc) < need) __builtin_amdgcn_s_sleep(1);
            }
            __syncthreads();
        }

        // ---- region 1: x part (k 0..127), fp32 sources, 3-term w/ register W_lo ----
#pragma unroll
        for (int ki = 0; ki < 4; ++ki) {
            float f[8];
            if (ki < 2) {
                const float* src = feats + ((size_t)brow * 159 + step) * 64 + ki * 32 + q * 8;
                f32x4 a = ((const f32x4*)src)[0];
                f32x4 b = ((const f32x4*)src)[1];
#pragma unroll
                for (int j = 0; j < 4; ++j) { f[j] = a[j]; f[4 + j] = b[j]; }
            } else if (!dec) {
                const float* src = labels + ((size_t)brow * 128 + step) * 64 + (ki - 2) * 32 + q * 8;
                f32x4 a = ((const f32x4*)src)[0];
                f32x4 b = ((const f32x4*)src)[1];
#pragma unroll
                for (int j = 0; j < 4; ++j) { f[j] = a[j]; f[4 + j] = b[j]; }
            } else {
                const u64* pp = (const u64*)(ps_f32 + (size_t)brow * 64 + (ki - 2) * 32 + q * 8);
#pragma unroll
                for (int j = 0; j < 4; ++j) {
                    u64 v = ldq_dev(pp + j);
                    f[2 * j]     = __uint_as_float((unsigned)v);
                    f[2 * j + 1] = __uint_as_float((unsigned)(v >> 32));
                }
            }
            short8 ah, al;
#pragma unroll
            for (int j = 0; j < 8; ++j) {
                short h2, l2;
                f2pair(f[j], h2, l2);
                ah[j] = h2; al[j] = l2;
            }
            const int fo = ((ki * 3) * 64 + lane) * 8;
            short8 b0 = *(const short8*)(s_whi + fo);
            short8 b1 = *(const short8*)(s_whi + fo + 512);
            short8 b2 = *(const short8*)(s_whi + fo + 1024);
            aR  = MFMA(ah, b0, aR);  aR  = MFMA(ah, L0r[ki], aR);  aR  = MFMA(al, b0, aR);
            aZ  = MFMA(ah, b1, aZ);  aZ  = MFMA(ah, L1r[ki], aZ);  aZ  = MFMA(al, b1, aZ);
            aNi = MFMA(ah, b2, aNi); aNi = MFMA(ah, L2r[ki], aNi); aNi = MFMA(al, b2, aNi);
        }

        // ---- epilogue: GRU update, fp32 hold, bf16-hi uncoherent publish ----
        {
            short* nh = h16 + (size_t)nxt * HB16;
#pragma unroll
            for (int i = 0; i < 4; ++i) {
                const int b = mbase + q * 4 + i;     // D row = (lane>>4)*4 + reg
                float rr = sigm(aR[i]);
                float zz = sigm(aZ[i]);
                float nn = tanh_fast(aNi[i] + rr * aNh[i]);
                float hv = (1.0f - zz) * nn + zz * hold[i];
                hold[i] = hv;
                st_nc16(nh + (size_t)b * 1024 + hcol,
                        (unsigned)(unsigned short)f2bf(hv));
            }
        }
        rbar(bcnt, bgen, (unsigned)step);   // publish h within r-group

        // ---- stage phase: octet copies r-slice of h(step+1) into local-XCD xbuf ----
        {
            const short* src = h16 + (size_t)nxt * HB16 + (size_t)r * XSLICE;
            short* dst = xbuf + (size_t)(myx * 4 + r) * XSLICE;
            for (int cidx = myidx * 512 + tid; cidx < 16384; cidx += g * 512) {
                i32x4 v = ld_nc16(src + (size_t)cidx * 8);
                WAITVM(0);
                st_c16(dst + (size_t)cidx * 8, v);
            }
            WAITVM(0);
            __syncthreads();
            if (tid == 0) addu_dev(xcnt, 1u);
        }

        // ---- ps phase: after encoder (step 127) and every decoder step ----
        if (step >= SENC - 1) {
            const int ot = step - (SENC - 1);        // output time 0..31
            const short* hnew = h16 + (size_t)nxt * HB16;
            const int prow0 = r * 128 + 2 * c;       // this block's 2 ps rows
            {
                const unsigned* hsrc = (const unsigned*)(hnew + (size_t)prow0 * 1024);
                unsigned pv0 = ldu_dev(hsrc + tid);
                unsigned pv1 = ldu_dev(hsrc + 512 + tid);
                s_ps[2 * tid]        = __uint_as_float(pv0 << 16);
                s_ps[2 * tid + 1]    = __uint_as_float(pv0 & 0xFFFF0000u);
                s_ps[1024 + 2 * tid] = __uint_as_float(pv1 << 16);
                s_ps[1025 + 2 * tid] = __uint_as_float(pv1 & 0xFFFF0000u);
            }
            __syncthreads();
            const int dot = tid >> 2, quar = tid & 3;
            const int rr2 = dot >> 6, o = dot & 63;
            const float* wrow = Wd + (size_t)o * 1024;
            const float* hrow = s_ps + rr2 * 1024;
            float acc = 0.0f;
#pragma unroll 8
            for (int j = 0; j < 64; ++j) {           // interleaved K-slices: conflict-free
                const int k = j * 16 + quar * 4;
                f32x4 w = *(const f32x4*)(wrow + k);
                f32x4 h4 = *(const f32x4*)(hrow + k);
                acc += h4[0] * w[0] + h4[1] * w[1] + h4[2] * w[2] + h4[3] * w[3];
            }
            acc += __shfl_xor(acc, 1);
            acc += __shfl_xor(acc, 2);
            if (quar == 0) {
                float v = acc + bd[o];
                out[((size_t)ot * 512 + prow0 + rr2) * 64 + o] = v;
                stf_dev(ps_f32 + (size_t)(prow0 + rr2) * 64 + o, v);
            }
            WAITVM(0);
            __syncthreads();
            if (tid == 0) addu_dev(psc, 1u);
            __syncthreads();
        }
    }
}

extern "C" void kernel_launch(void* const* d_in, const int* in_sizes, int n_in,
                              void* d_out, int out_size, void* d_ws, size_t ws_size,
                              hipStream_t stream) {
    const float* feats  = (const float*)d_in[0];
    const float* labels = (const float*)d_in[1];
    const float* Wi     = (const float*)d_in[2];
    const float* Wh     = (const float*)d_in[3];
    const float* bi     = (const float*)d_in[4];
    const float* bh     = (const float*)d_in[5];
    const float* Wd     = (const float*)d_in[6];
    const float* bd     = (const float*)d_in[7];
    float* out = (float*)d_out;

    char* ws = (char*)d_ws;
    short*    whi_sw = (short*)(ws);                   //  7,077,888 B
    short*    wlo_x  = (short*)(ws + 7077888);         //    786,432 B (x-part W_lo only)
    short*    h16    = (short*)(ws + 7864320);         //  2,097,152 B (2 buffers, bf16-hi)
    short*    xbuf   = (short*)(ws + 9961472);         //  8,388,608 B (8 XCD x 4 r slices)
    float*    ps_f32 = (float*)(ws + 18350080);        //    131,072 B
    unsigned* ctrl   = (unsigned*)(ws + 18481152);     //        512 B

    hipMemsetAsync(ctrl, 0, 512, stream);

    setup_swizzle<<<FRAG_TOTAL / 256, 256, 0, stream>>>(Wi, Wh, whi_sw, wlo_x);

    void* args[] = {(void*)&feats, (void*)&labels, (void*)&bi, (void*)&bh,
                    (void*)&Wd, (void*)&bd, (void*)&whi_sw, (void*)&wlo_x,
                    (void*)&h16, (void*)&xbuf, (void*)&ps_f32, (void*)&out,
                    (void*)&ctrl};
    hipLaunchCooperativeKernel(reinterpret_cast<void*>(gru_main),
                               dim3(256), dim3(512), args, 0, stream);
}

// Round 7
// 2568.434 us; speedup vs baseline: 4.6996x; 1.6613x over previous
//
#include <hip/hip_runtime.h>
#include <cstdint>
#include <cstddef>

// Problem constants
#define SENC  128
#define NSTEPS 159          // 128 encoder + 31 decoder
#define HB16  524288        // shorts per h buffer (512*1024)
#define XSLICE 131072       // shorts per (xcd,r) slice: 128*1024
#define SLAB_ELEMS 55296    // per-c W_hi slab: 36*3*64*8 shorts
#define FRAG_TOTAL 442368   // 64*36*3*64 fragment slots
#define FS 16               // flag stride in dwords (64B lines)

typedef short  short8  __attribute__((ext_vector_type(8)));
typedef float  floatx4 __attribute__((ext_vector_type(4)));
typedef float  f32x4   __attribute__((ext_vector_type(4)));
typedef int    i32x4   __attribute__((ext_vector_type(4)));
typedef unsigned long long u64;

#define MFMA(a, b, c) __builtin_amdgcn_mfma_f32_16x16x32_bf16((a), (b), (c), 0, 0, 0)

// ---------- raw asm memory ops ----------
// NOTE: asm "returns" the dest register immediately; the load lands only after
// s_waitcnt vmcnt. Results MUST live in singly-assigned named variables consumed
// after an explicit WAITVM — never stored through a runtime-variable index
// (forces a pre-wait register copy => garbage). This was the round-6 bug.
__device__ __forceinline__ i32x4 ld_nc16(const void* p) {      // bypass L1+L2 (coherence point)
    i32x4 r;
    asm volatile("global_load_dwordx4 %0, %1, off sc0 sc1" : "=&v"(r) : "v"(p) : "memory");
    return r;
}
__device__ __forceinline__ i32x4 ld_sc0_16(const void* p) {    // bypass L1, hit local L2
    i32x4 r;
    asm volatile("global_load_dwordx4 %0, %1, off sc0" : "=&v"(r) : "v"(p) : "memory");
    return r;
}
__device__ __forceinline__ void st_c16(void* p, i32x4 v) {     // plain cached store (own L2)
    asm volatile("global_store_dwordx4 %0, %1, off" :: "v"(p), "v"(v) : "memory");
}
__device__ __forceinline__ void st_nc8(void* p, u64 v) {       // uncoherent 8B store
    asm volatile("global_store_dwordx2 %0, %1, off sc0 sc1" :: "v"(p), "v"(v) : "memory");
}
#define WAITVM(N) asm volatile("s_waitcnt vmcnt(" #N ")" ::: "memory")
#define WAITLGKM  asm volatile("s_waitcnt lgkmcnt(0)" ::: "memory")

__device__ __forceinline__ int xcc_id() {
    unsigned v;
    asm volatile("s_getreg_b32 %0, hwreg(HW_REG_XCC_ID)" : "=s"(v));
    return (int)(v & 7);
}

// ---------- agent-scope relaxed atomics ----------
__device__ __forceinline__ unsigned ldu_dev(const unsigned* p) {
    return __hip_atomic_load(p, __ATOMIC_RELAXED, __HIP_MEMORY_SCOPE_AGENT);
}
__device__ __forceinline__ u64 ldq_dev(const u64* p) {
    return __hip_atomic_load(p, __ATOMIC_RELAXED, __HIP_MEMORY_SCOPE_AGENT);
}
__device__ __forceinline__ void stu_dev(unsigned* p, unsigned v) {
    __hip_atomic_store(p, v, __ATOMIC_RELAXED, __HIP_MEMORY_SCOPE_AGENT);
}
__device__ __forceinline__ void stf_dev(float* p, float v) {
    __hip_atomic_store(p, v, __ATOMIC_RELAXED, __HIP_MEMORY_SCOPE_AGENT);
}
__device__ __forceinline__ unsigned addu_dev(unsigned* p, unsigned v) {
    return __hip_atomic_fetch_add(p, v, __ATOMIC_RELAXED, __HIP_MEMORY_SCOPE_AGENT);
}

// ---------- bf16 helpers (RNE) ----------
__device__ __forceinline__ float bf2f(short s) {
    return __uint_as_float(((unsigned)(unsigned short)s) << 16);
}
__device__ __forceinline__ short f2bf(float f) {
    unsigned u = __float_as_uint(f);
    return (short)((u + 0x7FFFu + ((u >> 16) & 1u)) >> 16);
}
__device__ __forceinline__ void f2pair(float f, short& hi, short& lo) {
    hi = f2bf(f);
    lo = f2bf(f - bf2f(hi));
}

__device__ __forceinline__ float sigm(float x) {
    return 1.0f / (1.0f + __expf(-x));
}
__device__ __forceinline__ float tanh_fast(float x) {
    float cx = fminf(fmaxf(x, -15.0f), 15.0f);
    float e = __expf(2.0f * cx);
    return (e - 1.0f) / (e + 1.0f);
}

// ---------- setup: swizzle W_hi (all K) + Wi_lo (x-part only) into fragment order ----------
__global__ void setup_swizzle(const float* __restrict__ Wi, const float* __restrict__ Wh,
                              short* __restrict__ whi, short* __restrict__ wlo_x) {
    const int idx = blockIdx.x * 256 + threadIdx.x;
    if (idx >= FRAG_TOTAL) return;
    const int l    = idx & 63;
    const int rest = idx >> 6;
    const int t    = rest % 3;
    const int ki   = (rest / 3) % 36;
    const int c    = rest / 108;
    const int nrow = t * 1024 + c * 16 + (l & 15);
    const int kb   = ki * 32 + (l >> 4) * 8;
    short8 vh, vl;
#pragma unroll
    for (int j = 0; j < 8; ++j) {
        const int k = kb + j;
        float w = (k < 128) ? Wi[(size_t)nrow * 128 + k]
                            : Wh[(size_t)nrow * 1024 + (k - 128)];
        short h, lo2;
        f2pair(w, h, lo2);
        vh[j] = h; vl[j] = lo2;
    }
    *(short8*)(whi + (size_t)idx * 8) = vh;
    if (ki < 4) {
        const int xi = ((c * 4 + ki) * 3 + t) * 64 + l;
        *(short8*)(wlo_x + (size_t)xi * 8) = vl;
    }
}

// ---------- main persistent kernel ----------
__global__ __launch_bounds__(512, 2) void gru_main(
    const float* __restrict__ feats, const float* __restrict__ labels,
    const float* __restrict__ bi,    const float* __restrict__ bh,
    const float* __restrict__ Wd,    const float* __restrict__ bd,
    const short* __restrict__ whi_sw, const short* __restrict__ wlo_x,
    short* __restrict__ h16,         short* __restrict__ xbuf,
    float* __restrict__ ps_f32,      float* __restrict__ out,
    unsigned* __restrict__ ctrl,
    unsigned* __restrict__ hflag,    // [4r][64c] @64B
    unsigned* __restrict__ pflag,    // [4r][64c] @64B
    unsigned* __restrict__ sflag)    // [8x][4r][32i] @64B
{
    __shared__ short s_whi[SLAB_ELEMS];   // 108 KB resident W_hi slab (fragment order)
    __shared__ float s_ps[2048];          // ps-phase h staging (2 rows x 1024)
    __shared__ short s_tr[8][16][16];     // epilogue transpose tiles (4 KB)
    __shared__ int s_x, s_myidx, s_g;

    const int tid  = threadIdx.x;
    const int lane = tid & 63;
    const int wv   = tid >> 6;            // wave 0..7
    const int q    = lane >> 4;
    const int n16  = lane & 15;
    const int c    = blockIdx.x & 63;     // out-group: h-cols [16c, 16c+16)
    const int r    = blockIdx.x >> 6;     // batch-group: rows [128r, 128r+128)

    // ---- registration: dynamic (XCD, r) octet membership + one-shot grid gate.
    // ---- WAITVM(0) between the two RMWs: roster add must be processed at the
    // ---- coherence point before the gate add issues, else g reads can be stale.
    if (tid == 0) {
        const int x = xcc_id();
        s_x = x;
        s_myidx = (int)addu_dev(ctrl + 12 + x * 4 + r, 1u);
        WAITVM(0);
        unsigned o = addu_dev(ctrl + 76, 1u);
        if (o == 255u) stu_dev(ctrl + 77, 1u);
        else while (ldu_dev(ctrl + 77) < 1u) __builtin_amdgcn_s_sleep(1);
        s_g = (int)ldu_dev(ctrl + 12 + x * 4 + r);
    }

    // stage W_hi slab while registration settles
    {
        const f32x4* src = (const f32x4*)(whi_sw + (size_t)c * SLAB_ELEMS);
        f32x4* dst = (f32x4*)s_whi;
        for (int i = tid; i < SLAB_ELEMS / 8; i += 512) dst[i] = src[i];
    }
    __syncthreads();

    const int myx = s_x, myidx = s_myidx, g = s_g;
    const int mbase = r * 128 + wv * 16;  // this wave's 16 batch rows
    const int brow  = mbase + n16;        // A-fragment row for this lane
    const int row_r = c * 16 + n16;       // gate row == D col
    const float bias_r  = bi[row_r] + bh[row_r];
    const float bias_z  = bi[1024 + row_r] + bh[1024 + row_r];
    const float bias_ni = bi[2048 + row_r];
    const float bias_nh = bh[2048 + row_r];

    unsigned* my_hflag = hflag + (r * 64 + c) * FS;
    unsigned* my_pflag = pflag + (r * 64 + c) * FS;
    unsigned* my_sflag = sflag + ((myx * 4 + r) * 32 + myidx) * FS;
    unsigned* oct_sfl  = sflag + ((myx * 4 + r) * 32) * FS;
    unsigned* grp_hfl  = hflag + (r * 64) * FS;
    unsigned* grp_pfl  = pflag + (r * 64) * FS;

    // hoist region-1 W_lo fragments (step-invariant): 12 x short8 = 48 VGPRs
    short8 L0r[4], L1r[4], L2r[4];
#pragma unroll
    for (int ki = 0; ki < 4; ++ki) {
        const short* base = wlo_x + (size_t)(((c * 4 + ki) * 3) * 64 + lane) * 8;
        L0r[ki] = *(const short8*)(base);
        L1r[ki] = *(const short8*)(base + 512);
        L2r[ki] = *(const short8*)(base + 1024);
    }

    const short* xslice = xbuf + (size_t)(myx * 4 + r) * XSLICE;   // local-XCD replica
    const short* hrow0  = xslice + (size_t)(wv * 16 + n16) * 1024 + q * 8;

    float hold[4] = {0.f, 0.f, 0.f, 0.f};  // h carried fp32 in-register

    for (int step = 0; step < NSTEPS; ++step) {
        const int  nxt = (step & 1) ^ 1;
        const bool dec = (step >= SENC);
        const unsigned tgt = (unsigned)(step + 1);

        floatx4 aR  = (floatx4){bias_r,  bias_r,  bias_r,  bias_r};
        floatx4 aZ  = (floatx4){bias_z,  bias_z,  bias_z,  bias_z};
        floatx4 aNi = (floatx4){bias_ni, bias_ni, bias_ni, bias_ni};
        floatx4 aNh = (floatx4){bias_nh, bias_nh, bias_nh, bias_nh};

        // ---- stage-ready wait: xbuf holds h(step) ----
        if (step > 0) {
            if (wv == 0 && lane < g) {
                while (ldu_dev(oct_sfl + lane * FS) < (unsigned)step)
                    __builtin_amdgcn_s_sleep(1);
            }
            __syncthreads();

            // ---- region 2 (h part): local-L2 sc0 reads, depth-8 pipeline, 3 MFMA/ki ----
            i32x4 hb[8];
#define HISSUE(S, KI) hb[S] = ld_sc0_16(hrow0 + ((KI) - 4) * 32)
#define HCONS(S, KI) do { \
    short8 ah = *(short8*)&hb[S]; \
    const int fo_ = (((KI) * 3) * 64 + lane) * 8; \
    short8 b0 = *(const short8*)(s_whi + fo_); \
    short8 b1 = *(const short8*)(s_whi + fo_ + 512); \
    short8 b2 = *(const short8*)(s_whi + fo_ + 1024); \
    aR  = MFMA(ah, b0, aR); \
    aZ  = MFMA(ah, b1, aZ); \
    aNh = MFMA(ah, b2, aNh); \
} while (0)
            HISSUE(0, 4);  HISSUE(1, 5);  HISSUE(2, 6);  HISSUE(3, 7);
            HISSUE(4, 8);  HISSUE(5, 9);  HISSUE(6, 10); HISSUE(7, 11);
#pragma unroll
            for (int kb = 4; kb < 28; kb += 8) {
                WAITVM(7); HCONS(0, kb + 0); HISSUE(0, kb + 8);
                WAITVM(7); HCONS(1, kb + 1); HISSUE(1, kb + 9);
                WAITVM(7); HCONS(2, kb + 2); HISSUE(2, kb + 10);
                WAITVM(7); HCONS(3, kb + 3); HISSUE(3, kb + 11);
                WAITVM(7); HCONS(4, kb + 4); HISSUE(4, kb + 12);
                WAITVM(7); HCONS(5, kb + 5); HISSUE(5, kb + 13);
                WAITVM(7); HCONS(6, kb + 6); HISSUE(6, kb + 14);
                WAITVM(7); HCONS(7, kb + 7); HISSUE(7, kb + 15);
            }
            WAITVM(7); HCONS(0, 28);
            WAITVM(6); HCONS(1, 29);
            WAITVM(5); HCONS(2, 30);
            WAITVM(4); HCONS(3, 31);
            WAITVM(3); HCONS(4, 32);
            WAITVM(2); HCONS(5, 33);
            WAITVM(1); HCONS(6, 34);
            WAITVM(0); HCONS(7, 35);
#undef HISSUE
#undef HCONS
        }

        // ---- ps-ready wait (decoder): ps(step) published during step-1 ----
        if (dec) {
            if (wv == 0) {
                while (ldu_dev(grp_pfl + lane * FS) < (unsigned)step)
                    __builtin_amdgcn_s_sleep(1);
            }
            __syncthreads();
        }

        // ---- region 1: x part (k 0..127), fp32 sources, 3-term w/ register W_lo ----
#pragma unroll
        for (int ki = 0; ki < 4; ++ki) {
            float f[8];
            if (ki < 2) {
                const float* src = feats + ((size_t)brow * 159 + step) * 64 + ki * 32 + q * 8;
                f32x4 a = ((const f32x4*)src)[0];
                f32x4 b = ((const f32x4*)src)[1];
#pragma unroll
                for (int j = 0; j < 4; ++j) { f[j] = a[j]; f[4 + j] = b[j]; }
            } else if (!dec) {
                const float* src = labels + ((size_t)brow * 128 + step) * 64 + (ki - 2) * 32 + q * 8;
                f32x4 a = ((const f32x4*)src)[0];
                f32x4 b = ((const f32x4*)src)[1];
#pragma unroll
                for (int j = 0; j < 4; ++j) { f[j] = a[j]; f[4 + j] = b[j]; }
            } else {
                const u64* pp = (const u64*)(ps_f32 + (size_t)brow * 64 + (ki - 2) * 32 + q * 8);
#pragma unroll
                for (int j = 0; j < 4; ++j) {
                    u64 v = ldq_dev(pp + j);
                    f[2 * j]     = __uint_as_float((unsigned)v);
                    f[2 * j + 1] = __uint_as_float((unsigned)(v >> 32));
                }
            }
            short8 ah, al;
#pragma unroll
            for (int j = 0; j < 8; ++j) {
                short h2, l2;
                f2pair(f[j], h2, l2);
                ah[j] = h2; al[j] = l2;
            }
            const int fo = ((ki * 3) * 64 + lane) * 8;
            short8 b0 = *(const short8*)(s_whi + fo);
            short8 b1 = *(const short8*)(s_whi + fo + 512);
            short8 b2 = *(const short8*)(s_whi + fo + 1024);
            aR  = MFMA(ah, b0, aR);  aR  = MFMA(ah, L0r[ki], aR);  aR  = MFMA(al, b0, aR);
            aZ  = MFMA(ah, b1, aZ);  aZ  = MFMA(ah, L1r[ki], aZ);  aZ  = MFMA(al, b1, aZ);
            aNi = MFMA(ah, b2, aNi); aNi = MFMA(ah, L2r[ki], aNi); aNi = MFMA(al, b2, aNi);
        }

        // ---- epilogue: GRU update; coalesced publish via per-wave LDS transpose ----
        {
#pragma unroll
            for (int i = 0; i < 4; ++i) {
                float rr = sigm(aR[i]);
                float zz = sigm(aZ[i]);
                float nn = tanh_fast(aNi[i] + rr * aNh[i]);
                float hv = (1.0f - zz) * nn + zz * hold[i];
                hold[i] = hv;
                s_tr[wv][q * 4 + i][n16] = f2bf(hv);   // D row = q*4+i, col = n16
            }
            WAITLGKM;
            const int rr2 = lane >> 2, seg = lane & 3;
            u64 v = *(const u64*)&s_tr[wv][rr2][seg * 4];
            st_nc8(h16 + (size_t)nxt * HB16 + (size_t)(mbase + rr2) * 1024 + c * 16 + seg * 4, v);
            WAITVM(0);
        }
        __syncthreads();
        if (tid == 0) stu_dev(my_hflag, tgt);          // arrive: h(step+1) published

        // ---- h-barrier: poll all 64 r-group flags (distributed, no shared counter) ----
        if (wv == 0) {
            while (ldu_dev(grp_hfl + lane * FS) < tgt)
                __builtin_amdgcn_s_sleep(1);
        }
        __syncthreads();

        // ---- stage phase: octet copies r-slice of h(step+1) into local-XCD xbuf.
        // ---- named regs only (no variable-indexed asm outputs — round-6 bug).
        {
            const short* src = h16 + (size_t)nxt * HB16 + (size_t)r * XSLICE;
            short* dst = xbuf + (size_t)(myx * 4 + r) * XSLICE;
            if (g == 8) {
                const int base = myidx * 512 + tid;    // 0..4095
                i32x4 v0 = ld_nc16(src + (size_t)(base        ) * 8);
                i32x4 v1 = ld_nc16(src + (size_t)(base +  4096) * 8);
                i32x4 v2 = ld_nc16(src + (size_t)(base +  8192) * 8);
                i32x4 v3 = ld_nc16(src + (size_t)(base + 12288) * 8);
                WAITVM(0);
                st_c16(dst + (size_t)(base        ) * 8, v0);
                st_c16(dst + (size_t)(base +  4096) * 8, v1);
                st_c16(dst + (size_t)(base +  8192) * 8, v2);
                st_c16(dst + (size_t)(base + 12288) * 8, v3);
            } else {
                for (int cidx = myidx * 512 + tid; cidx < 16384; cidx += g * 512) {
                    i32x4 v = ld_nc16(src + (size_t)cidx * 8);
                    WAITVM(0);
                    st_c16(dst + (size_t)cidx * 8, v);
                }
            }
            WAITVM(0);
            __syncthreads();
            if (tid == 0) stu_dev(my_sflag, tgt);      // xbuf holds h(step+1)
        }

        // ---- ps phase: after encoder (step 127) and every decoder step ----
        if (step >= SENC - 1) {
            const int ot = step - (SENC - 1);          // output time 0..31
            const int prow0 = r * 128 + 2 * c;         // this block's 2 ps rows
            {
                const unsigned* hsrc = (const unsigned*)(h16 + (size_t)nxt * HB16 + (size_t)prow0 * 1024);
                unsigned pv0 = ldu_dev(hsrc + tid);
                unsigned pv1 = ldu_dev(hsrc + 512 + tid);
                s_ps[2 * tid]        = __uint_as_float(pv0 << 16);
                s_ps[2 * tid + 1]    = __uint_as_float(pv0 & 0xFFFF0000u);
                s_ps[1024 + 2 * tid] = __uint_as_float(pv1 << 16);
                s_ps[1025 + 2 * tid] = __uint_as_float(pv1 & 0xFFFF0000u);
            }
            __syncthreads();
            const int dot = tid >> 2, quar = tid & 3;
            const int rr2 = dot >> 6, o = dot & 63;
            const float* wrow = Wd + (size_t)o * 1024;
            const float* hrow = s_ps + rr2 * 1024;
            float acc = 0.0f;
#pragma unroll 8
            for (int j = 0; j < 64; ++j) {             // interleaved K-slices: conflict-free
                const int k = j * 16 + quar * 4;
                f32x4 w = *(const f32x4*)(wrow + k);
                f32x4 h4 = *(const f32x4*)(hrow + k);
                acc += h4[0] * w[0] + h4[1] * w[1] + h4[2] * w[2] + h4[3] * w[3];
            }
            acc += __shfl_xor(acc, 1);
            acc += __shfl_xor(acc, 2);
            if (quar == 0) {
                float v = acc + bd[o];
                out[((size_t)ot * 512 + prow0 + rr2) * 64 + o] = v;
                stf_dev(ps_f32 + (size_t)(prow0 + rr2) * 64 + o, v);
            }
            WAITVM(0);
            __syncthreads();
            if (tid == 0) stu_dev(my_pflag, tgt);      // ps(step+1) published
        }
    }
}

extern "C" void kernel_launch(void* const* d_in, const int* in_sizes, int n_in,
                              void* d_out, int out_size, void* d_ws, size_t ws_size,
                              hipStream_t stream) {
    const float* feats  = (const float*)d_in[0];
    const float* labels = (const float*)d_in[1];
    const float* Wi     = (const float*)d_in[2];
    const float* Wh     = (const float*)d_in[3];
    const float* bi     = (const float*)d_in[4];
    const float* bh     = (const float*)d_in[5];
    const float* Wd     = (const float*)d_in[6];
    const float* bd     = (const float*)d_in[7];
    float* out = (float*)d_out;

    char* ws = (char*)d_ws;
    short*    whi_sw = (short*)(ws);                   //  7,077,888 B
    short*    wlo_x  = (short*)(ws + 7077888);         //    786,432 B
    short*    h16    = (short*)(ws + 7864320);         //  2,097,152 B (2 buffers, bf16-hi)
    short*    xbuf   = (short*)(ws + 9961472);         //  8,388,608 B (8 XCD x 4 r slices)
    float*    ps_f32 = (float*)(ws + 18350080);        //    131,072 B
    unsigned* ctrl   = (unsigned*)(ws + 18481152);     //        512 B
    unsigned* hflag  = (unsigned*)(ws + 18481664);     //     16,384 B (4r x 64c x 64B)
    unsigned* pflag  = (unsigned*)(ws + 18498048);     //     16,384 B
    unsigned* sflag  = (unsigned*)(ws + 18514432);     //     65,536 B (8x x 4r x 32i x 64B)

    // zero all sync state (ctrl + flags); h16/xbuf fully written before any read
    hipMemsetAsync(ctrl, 0, 98816, stream);

    setup_swizzle<<<FRAG_TOTAL / 256, 256, 0, stream>>>(Wi, Wh, whi_sw, wlo_x);

    void* args[] = {(void*)&feats, (void*)&labels, (void*)&bi, (void*)&bh,
                    (void*)&Wd, (void*)&bd, (void*)&whi_sw, (void*)&wlo_x,
                    (void*)&h16, (void*)&xbuf, (void*)&ps_f32, (void*)&out,
                    (void*)&ctrl, (void*)&hflag, (void*)&pflag, (void*)&sflag};
    hipLaunchCooperativeKernel(reinterpret_cast<void*>(gru_main),
                               dim3(256), dim3(512), args, 0, stream);
}

// Round 8
// 2342.050 us; speedup vs baseline: 5.1539x; 1.0967x over previous
//
#include <hip/hip_runtime.h>
#include <cstdint>
#include <cstddef>

// Problem constants
#define SENC  128
#define NSTEPS 159          // 128 encoder + 31 decoder
#define HB16  524288        // shorts per h buffer (512*1024), tile-major [r][c][128][16]
#define XSLICE 131072       // shorts per (xcd,r) slice: 64 tiles x 2048
#define SLAB_ELEMS 55296    // per-c W_hi slab: 36*3*64*8 shorts
#define FRAG_TOTAL 442368   // 64*36*3*64 fragment slots
#define FS 16               // flag stride in dwords (64B lines)

typedef short  short8  __attribute__((ext_vector_type(8)));
typedef float  floatx4 __attribute__((ext_vector_type(4)));
typedef float  f32x4   __attribute__((ext_vector_type(4)));
typedef int    i32x4   __attribute__((ext_vector_type(4)));
typedef unsigned long long u64;

#define MFMA(a, b, c) __builtin_amdgcn_mfma_f32_16x16x32_bf16((a), (b), (c), 0, 0, 0)

// ---------- raw asm memory ops ----------
// Discipline: asm load results live in singly-assigned named variables consumed
// only after an explicit WAITVM (round-6 lesson: never variable-indexed dests).
__device__ __forceinline__ i32x4 ld_nc16(const void* p) {      // bypass L1+L2 (coherence point)
    i32x4 r;
    asm volatile("global_load_dwordx4 %0, %1, off sc0 sc1" : "=&v"(r) : "v"(p) : "memory");
    return r;
}
__device__ __forceinline__ i32x4 ld_sc0_16(const void* p) {    // bypass L1, hit local L2
    i32x4 r;
    asm volatile("global_load_dwordx4 %0, %1, off sc0" : "=&v"(r) : "v"(p) : "memory");
    return r;
}
__device__ __forceinline__ void st_c16(void* p, i32x4 v) {     // plain cached store (own L2)
    asm volatile("global_store_dwordx4 %0, %1, off" :: "v"(p), "v"(v) : "memory");
}
__device__ __forceinline__ void st_nc8(void* p, u64 v) {       // uncoherent 8B store
    asm volatile("global_store_dwordx2 %0, %1, off sc0 sc1" :: "v"(p), "v"(v) : "memory");
}
#define WAITVM(N) asm volatile("s_waitcnt vmcnt(" #N ")" ::: "memory")
#define WAITLGKM  asm volatile("s_waitcnt lgkmcnt(0)" ::: "memory")

__device__ __forceinline__ int xcc_id() {
    unsigned v;
    asm volatile("s_getreg_b32 %0, hwreg(HW_REG_XCC_ID)" : "=s"(v));
    return (int)(v & 7);
}

// ---------- agent-scope relaxed atomics ----------
__device__ __forceinline__ unsigned ldu_dev(const unsigned* p) {
    return __hip_atomic_load(p, __ATOMIC_RELAXED, __HIP_MEMORY_SCOPE_AGENT);
}
__device__ __forceinline__ u64 ldq_dev(const u64* p) {
    return __hip_atomic_load(p, __ATOMIC_RELAXED, __HIP_MEMORY_SCOPE_AGENT);
}
__device__ __forceinline__ void stu_dev(unsigned* p, unsigned v) {
    __hip_atomic_store(p, v, __ATOMIC_RELAXED, __HIP_MEMORY_SCOPE_AGENT);
}
__device__ __forceinline__ void stf_dev(float* p, float v) {
    __hip_atomic_store(p, v, __ATOMIC_RELAXED, __HIP_MEMORY_SCOPE_AGENT);
}
__device__ __forceinline__ unsigned addu_dev(unsigned* p, unsigned v) {
    return __hip_atomic_fetch_add(p, v, __ATOMIC_RELAXED, __HIP_MEMORY_SCOPE_AGENT);
}

// ---------- bf16 helpers (RNE) ----------
__device__ __forceinline__ float bf2f(short s) {
    return __uint_as_float(((unsigned)(unsigned short)s) << 16);
}
__device__ __forceinline__ short f2bf(float f) {
    unsigned u = __float_as_uint(f);
    return (short)((u + 0x7FFFu + ((u >> 16) & 1u)) >> 16);
}
__device__ __forceinline__ void f2pair(float f, short& hi, short& lo) {
    hi = f2bf(f);
    lo = f2bf(f - bf2f(hi));
}

__device__ __forceinline__ float sigm(float x) {
    return 1.0f / (1.0f + __expf(-x));
}
__device__ __forceinline__ float tanh_fast(float x) {
    float cx = fminf(fmaxf(x, -15.0f), 15.0f);
    float e = __expf(2.0f * cx);
    return (e - 1.0f) / (e + 1.0f);
}

// ---------- setup: swizzle W_hi (all K) + Wi_lo (x-part only) into fragment order ----------
__global__ void setup_swizzle(const float* __restrict__ Wi, const float* __restrict__ Wh,
                              short* __restrict__ whi, short* __restrict__ wlo_x) {
    const int idx = blockIdx.x * 256 + threadIdx.x;
    if (idx >= FRAG_TOTAL) return;
    const int l    = idx & 63;
    const int rest = idx >> 6;
    const int t    = rest % 3;
    const int ki   = (rest / 3) % 36;
    const int c    = rest / 108;
    const int nrow = t * 1024 + c * 16 + (l & 15);
    const int kb   = ki * 32 + (l >> 4) * 8;
    short8 vh, vl;
#pragma unroll
    for (int j = 0; j < 8; ++j) {
        const int k = kb + j;
        float w = (k < 128) ? Wi[(size_t)nrow * 128 + k]
                            : Wh[(size_t)nrow * 1024 + (k - 128)];
        short h, lo2;
        f2pair(w, h, lo2);
        vh[j] = h; vl[j] = lo2;
    }
    *(short8*)(whi + (size_t)idx * 8) = vh;
    if (ki < 4) {
        const int xi = ((c * 4 + ki) * 3 + t) * 64 + l;
        *(short8*)(wlo_x + (size_t)xi * 8) = vl;
    }
}

// ---------- main persistent kernel ----------
__global__ __launch_bounds__(512, 2) void gru_main(
    const float* __restrict__ feats, const float* __restrict__ labels,
    const float* __restrict__ bi,    const float* __restrict__ bh,
    const float* __restrict__ Wd,    const float* __restrict__ bd,
    const short* __restrict__ whi_sw, const short* __restrict__ wlo_x,
    short* __restrict__ h16,         short* __restrict__ xbuf,
    float* __restrict__ ps_f32,      float* __restrict__ out,
    unsigned* __restrict__ ctrl,     // [0..77] reg/gate, [128..1151] roster
    unsigned* __restrict__ hflag,    // [4r][64c] @64B
    unsigned* __restrict__ pflag,    // [4r][64c] @64B
    unsigned* __restrict__ sflag)    // [8x][4r][32i] @64B
{
    __shared__ short s_whi[SLAB_ELEMS];   // 108 KB resident W_hi slab (fragment order)
    __shared__ float s_ps[2048];          // ps-phase h staging (2 rows x 1024)
    __shared__ short s_tr[8][16][18];     // epilogue transpose tiles (padded: bank-safe)
    __shared__ unsigned s_roster[32];     // octet member -> c
    __shared__ int s_x, s_myidx, s_g;

    const int tid  = threadIdx.x;
    const int lane = tid & 63;
    const int wv   = tid >> 6;            // wave 0..7
    const int q    = lane >> 4;
    const int n16  = lane & 15;
    const int c    = blockIdx.x & 63;     // out-group: h-cols [16c, 16c+16)
    const int r    = blockIdx.x >> 6;     // batch-group: rows [128r, 128r+128)

    unsigned* roster = ctrl + 128;

    // ---- registration: dynamic (XCD, r) octet membership + roster + grid gate ----
    if (tid == 0) {
        const int x = xcc_id();
        s_x = x;
        int mi = (int)addu_dev(ctrl + 12 + x * 4 + r, 1u);
        s_myidx = mi;
        WAITVM(0);
        stu_dev(roster + (x * 4 + r) * 32 + mi, (unsigned)c);
        WAITVM(0);
        unsigned o = addu_dev(ctrl + 76, 1u);
        if (o == 255u) stu_dev(ctrl + 77, 1u);
        else while (ldu_dev(ctrl + 77) < 1u) __builtin_amdgcn_s_sleep(1);
        s_g = (int)ldu_dev(ctrl + 12 + x * 4 + r);
    }

    // stage W_hi slab while registration settles
    {
        const f32x4* src = (const f32x4*)(whi_sw + (size_t)c * SLAB_ELEMS);
        f32x4* dst = (f32x4*)s_whi;
        for (int i = tid; i < SLAB_ELEMS / 8; i += 512) dst[i] = src[i];
    }
    __syncthreads();

    const int myx = s_x, myidx = s_myidx, g = s_g;
    if (tid < 32) s_roster[tid] = (tid < g) ? ldu_dev(roster + (myx * 4 + r) * 32 + tid) : 0u;
    __syncthreads();

    const int mbase = r * 128 + wv * 16;  // this wave's 16 batch rows (global)
    const int brow  = mbase + n16;        // A-fragment row for this lane
    const int row_r = c * 16 + n16;       // gate row == D col
    const float bias_r  = bi[row_r] + bh[row_r];
    const float bias_z  = bi[1024 + row_r] + bh[1024 + row_r];
    const float bias_ni = bi[2048 + row_r];
    const float bias_nh = bh[2048 + row_r];

    unsigned* my_hflag = hflag + (r * 64 + c) * FS;
    unsigned* my_pflag = pflag + (r * 64 + c) * FS;
    unsigned* my_sflag = sflag + ((myx * 4 + r) * 32 + myidx) * FS;
    unsigned* oct_sfl  = sflag + ((myx * 4 + r) * 32) * FS;
    unsigned* grp_hfl  = hflag + (r * 64) * FS;
    unsigned* grp_pfl  = pflag + (r * 64) * FS;

    // hoist region-1 W_lo fragments (step-invariant): 12 x short8 = 48 VGPRs
    short8 L0r[4], L1r[4], L2r[4];
#pragma unroll
    for (int ki = 0; ki < 4; ++ki) {
        const short* base = wlo_x + (size_t)(((c * 4 + ki) * 3) * 64 + lane) * 8;
        L0r[ki] = *(const short8*)(base);
        L1r[ki] = *(const short8*)(base + 512);
        L2r[ki] = *(const short8*)(base + 1024);
    }

    // region2 read base in local-XCD replica (tile-major):
    // k = (ki-4)*32 + q*8 -> tile (ki-4)*2+(q>>1), col (q&1)*8
    short* xsl_w = xbuf + (size_t)(myx * 4 + r) * XSLICE;
    const short* hrow0 = xsl_w + (size_t)(wv * 16 + n16) * 16 + (q & 1) * 8 + (q >> 1) * 2048;

    float hold[4] = {0.f, 0.f, 0.f, 0.f};  // h carried fp32 in-register

    for (int step = 0; step < NSTEPS; ++step) {
        const int  nxt = (step & 1) ^ 1;
        const bool dec = (step >= SENC);
        const unsigned tgt = (unsigned)(step + 1);

        floatx4 aR  = (floatx4){bias_r,  bias_r,  bias_r,  bias_r};
        floatx4 aZ  = (floatx4){bias_z,  bias_z,  bias_z,  bias_z};
        floatx4 aNi = (floatx4){bias_ni, bias_ni, bias_ni, bias_ni};
        floatx4 aNh = (floatx4){bias_nh, bias_nh, bias_nh, bias_nh};

        // ---- stage-ready wait: local xbuf holds h(step) ----
        if (step > 0) {
            if (wv == 0 && lane < g) {
                while (ldu_dev(oct_sfl + lane * FS) < (unsigned)step)
                    __builtin_amdgcn_s_sleep(1);
            }
            __syncthreads();

            // ---- region 2 (h part): local-L2 sc0 reads, depth-8 pipeline, 3 MFMA/ki ----
            i32x4 hb[8];
#define HISSUE(S, KI) hb[S] = ld_sc0_16(hrow0 + ((KI) - 4) * 4096)
#define HCONS(S, KI) do { \
    short8 ah = *(short8*)&hb[S]; \
    const int fo_ = (((KI) * 3) * 64 + lane) * 8; \
    short8 b0 = *(const short8*)(s_whi + fo_); \
    short8 b1 = *(const short8*)(s_whi + fo_ + 512); \
    short8 b2 = *(const short8*)(s_whi + fo_ + 1024); \
    aR  = MFMA(ah, b0, aR); \
    aZ  = MFMA(ah, b1, aZ); \
    aNh = MFMA(ah, b2, aNh); \
} while (0)
            HISSUE(0, 4);  HISSUE(1, 5);  HISSUE(2, 6);  HISSUE(3, 7);
            HISSUE(4, 8);  HISSUE(5, 9);  HISSUE(6, 10); HISSUE(7, 11);
#pragma unroll
            for (int kb = 4; kb < 28; kb += 8) {
                WAITVM(7); HCONS(0, kb + 0); HISSUE(0, kb + 8);
                WAITVM(7); HCONS(1, kb + 1); HISSUE(1, kb + 9);
                WAITVM(7); HCONS(2, kb + 2); HISSUE(2, kb + 10);
                WAITVM(7); HCONS(3, kb + 3); HISSUE(3, kb + 11);
                WAITVM(7); HCONS(4, kb + 4); HISSUE(4, kb + 12);
                WAITVM(7); HCONS(5, kb + 5); HISSUE(5, kb + 13);
                WAITVM(7); HCONS(6, kb + 6); HISSUE(6, kb + 14);
                WAITVM(7); HCONS(7, kb + 7); HISSUE(7, kb + 15);
            }
            WAITVM(7); HCONS(0, 28);
            WAITVM(6); HCONS(1, 29);
            WAITVM(5); HCONS(2, 30);
            WAITVM(4); HCONS(3, 31);
            WAITVM(3); HCONS(4, 32);
            WAITVM(2); HCONS(5, 33);
            WAITVM(1); HCONS(6, 34);
            WAITVM(0); HCONS(7, 35);
#undef HISSUE
#undef HCONS
        }

        // ---- ps-ready wait (decoder): ps(step) published during step-1 ----
        if (dec) {
            if (wv == 0) {
                while (ldu_dev(grp_pfl + lane * FS) < (unsigned)step)
                    __builtin_amdgcn_s_sleep(1);
            }
            __syncthreads();
        }

        // ---- region 1: x part (k 0..127), fp32 sources, 3-term w/ register W_lo ----
#pragma unroll
        for (int ki = 0; ki < 4; ++ki) {
            float f[8];
            if (ki < 2) {
                const float* src = feats + ((size_t)brow * 159 + step) * 64 + ki * 32 + q * 8;
                f32x4 a = ((const f32x4*)src)[0];
                f32x4 b = ((const f32x4*)src)[1];
#pragma unroll
                for (int j = 0; j < 4; ++j) { f[j] = a[j]; f[4 + j] = b[j]; }
            } else if (!dec) {
                const float* src = labels + ((size_t)brow * 128 + step) * 64 + (ki - 2) * 32 + q * 8;
                f32x4 a = ((const f32x4*)src)[0];
                f32x4 b = ((const f32x4*)src)[1];
#pragma unroll
                for (int j = 0; j < 4; ++j) { f[j] = a[j]; f[4 + j] = b[j]; }
            } else {
                const u64* pp = (const u64*)(ps_f32 + (size_t)brow * 64 + (ki - 2) * 32 + q * 8);
#pragma unroll
                for (int j = 0; j < 4; ++j) {
                    u64 v = ldq_dev(pp + j);
                    f[2 * j]     = __uint_as_float((unsigned)v);
                    f[2 * j + 1] = __uint_as_float((unsigned)(v >> 32));
                }
            }
            short8 ah, al;
#pragma unroll
            for (int j = 0; j < 8; ++j) {
                short h2, l2;
                f2pair(f[j], h2, l2);
                ah[j] = h2; al[j] = l2;
            }
            const int fo = ((ki * 3) * 64 + lane) * 8;
            short8 b0 = *(const short8*)(s_whi + fo);
            short8 b1 = *(const short8*)(s_whi + fo + 512);
            short8 b2 = *(const short8*)(s_whi + fo + 1024);
            aR  = MFMA(ah, b0, aR);  aR  = MFMA(ah, L0r[ki], aR);  aR  = MFMA(al, b0, aR);
            aZ  = MFMA(ah, b1, aZ);  aZ  = MFMA(ah, L1r[ki], aZ);  aZ  = MFMA(al, b1, aZ);
            aNi = MFMA(ah, b2, aNi); aNi = MFMA(ah, L2r[ki], aNi); aNi = MFMA(al, b2, aNi);
        }

        // ---- epilogue: GRU update; publish own 4KB tile contiguously (tile-major) ----
        {
#pragma unroll
            for (int i = 0; i < 4; ++i) {
                float rr = sigm(aR[i]);
                float zz = sigm(aZ[i]);
                float nn = tanh_fast(aNi[i] + rr * aNh[i]);
                float hv = (1.0f - zz) * nn + zz * hold[i];
                hold[i] = hv;
                s_tr[wv][q * 4 + i][n16] = f2bf(hv);   // D row = q*4+i, col = n16
            }
            WAITLGKM;
            const int rr2 = lane >> 2, seg = lane & 3;
            u64 v = *(const u64*)&s_tr[wv][rr2][seg * 4];
            st_nc8(h16 + (size_t)nxt * HB16 + (size_t)r * XSLICE + (size_t)c * 2048
                       + (size_t)(wv * 16 + rr2) * 16 + seg * 4, v);
            WAITVM(0);
        }
        __syncthreads();
        if (tid == 0) stu_dev(my_hflag, tgt);          // h-tile(step+1) published

        // ---- stage-guard: all octet members finished region2(step) reads of xbuf ----
        if (wv == 0 && lane < g) {
            const unsigned* mf = hflag + (r * 64 + (int)s_roster[lane]) * FS;
            while (ldu_dev(mf) < tgt) __builtin_amdgcn_s_sleep(1);
        }
        __syncthreads();

        // ---- stage: copy h(step+1) tiles into local-XCD xbuf (fine-grained flags) ----
        {
            const short* srcSlice = h16 + (size_t)nxt * HB16 + (size_t)r * XSLICE;
            if (g == 8) {
                const int cp = myidx * 8 + wv;         // this wave's producer tile
                const unsigned* pf = hflag + (r * 64 + cp) * FS;
                while (ldu_dev(pf) < tgt) __builtin_amdgcn_s_sleep(1);
                const short* sb = srcSlice + (size_t)cp * 2048 + lane * 32;
                short* db = xsl_w + (size_t)cp * 2048 + lane * 32;
                i32x4 v0 = ld_nc16(sb);
                i32x4 v1 = ld_nc16(sb + 8);
                i32x4 v2 = ld_nc16(sb + 16);
                i32x4 v3 = ld_nc16(sb + 24);
                WAITVM(0);
                st_c16(db,      v0);
                st_c16(db +  8, v1);
                st_c16(db + 16, v2);
                st_c16(db + 24, v3);
            } else {
                if (wv == 0) {                          // generic: wait all producers
                    while (ldu_dev(grp_hfl + lane * FS) < tgt)
                        __builtin_amdgcn_s_sleep(1);
                }
                __syncthreads();
                for (int cidx = myidx * 512 + tid; cidx < 16384; cidx += g * 512) {
                    i32x4 v = ld_nc16(srcSlice + (size_t)cidx * 8);
                    WAITVM(0);
                    st_c16(xsl_w + (size_t)cidx * 8, v);
                }
            }
            WAITVM(0);
            __syncthreads();
            if (tid == 0) stu_dev(my_sflag, tgt);      // local xbuf holds h(step+1)
        }

        // ---- ps phase: after encoder (step 127) and every decoder step ----
        if (step >= SENC - 1) {
            const int ot = step - (SENC - 1);          // output time 0..31
            const int prow0 = r * 128 + 2 * c;         // this block's 2 ps rows (global)
            if (wv == 0) {                              // need ALL producers' h rows
                while (ldu_dev(grp_hfl + lane * FS) < tgt)
                    __builtin_amdgcn_s_sleep(1);
            }
            __syncthreads();
            if (tid < 256) {                            // 2 rows x 1024 cols, tile-major gather
                const int rl = tid >> 7, rest = tid & 127;
                const int ct = rest >> 1, half = rest & 1;
                const short* src = h16 + (size_t)nxt * HB16 + (size_t)r * XSLICE
                                 + (size_t)ct * 2048 + (size_t)(2 * c + rl) * 16 + half * 8;
                i32x4 v = ld_nc16(src);
                WAITVM(0);
                short8 s = *(short8*)&v;
#pragma unroll
                for (int j = 0; j < 8; ++j)
                    s_ps[rl * 1024 + ct * 16 + half * 8 + j] = bf2f(s[j]);
            }
            __syncthreads();
            const int dot = tid >> 2, quar = tid & 3;
            const int rr2 = dot >> 6, o = dot & 63;
            const float* wrow = Wd + (size_t)o * 1024;
            const float* hrow = s_ps + rr2 * 1024;
            float acc = 0.0f;
#pragma unroll 8
            for (int j = 0; j < 64; ++j) {             // interleaved K-slices: conflict-free
                const int k = j * 16 + quar * 4;
                f32x4 w = *(const f32x4*)(wrow + k);
                f32x4 h4 = *(const f32x4*)(hrow + k);
                acc += h4[0] * w[0] + h4[1] * w[1] + h4[2] * w[2] + h4[3] * w[3];
            }
            acc += __shfl_xor(acc, 1);
            acc += __shfl_xor(acc, 2);
            if (quar == 0) {
                float v = acc + bd[o];
                out[((size_t)ot * 512 + prow0 + rr2) * 64 + o] = v;
                stf_dev(ps_f32 + (size_t)(prow0 + rr2) * 64 + o, v);
            }
            WAITVM(0);
            __syncthreads();
            if (tid == 0) stu_dev(my_pflag, tgt);      // ps(step+1) published
        }
    }
}

extern "C" void kernel_launch(void* const* d_in, const int* in_sizes, int n_in,
                              void* d_out, int out_size, void* d_ws, size_t ws_size,
                              hipStream_t stream) {
    const float* feats  = (const float*)d_in[0];
    const float* labels = (const float*)d_in[1];
    const float* Wi     = (const float*)d_in[2];
    const float* Wh     = (const float*)d_in[3];
    const float* bi     = (const float*)d_in[4];
    const float* bh     = (const float*)d_in[5];
    const float* Wd     = (const float*)d_in[6];
    const float* bd     = (const float*)d_in[7];
    float* out = (float*)d_out;

    char* ws = (char*)d_ws;
    short*    whi_sw = (short*)(ws);                   //  7,077,888 B
    short*    wlo_x  = (short*)(ws + 7077888);         //    786,432 B
    short*    h16    = (short*)(ws + 7864320);         //  2,097,152 B (2 buffers, tile-major)
    short*    xbuf   = (short*)(ws + 9961472);         //  8,388,608 B (8 XCD x 4 r slices)
    float*    ps_f32 = (float*)(ws + 18350080);        //    131,072 B
    unsigned* ctrl   = (unsigned*)(ws + 18481152);     //      8,192 B (reg/gate + roster)
    unsigned* hflag  = (unsigned*)(ws + 18489344);     //     16,384 B (4r x 64c x 64B)
    unsigned* pflag  = (unsigned*)(ws + 18505728);     //     16,384 B
    unsigned* sflag  = (unsigned*)(ws + 18522112);     //     65,536 B (8x x 4r x 32i x 64B)

    // zero all sync state (ctrl + roster + flags)
    hipMemsetAsync(ctrl, 0, 106496, stream);

    setup_swizzle<<<FRAG_TOTAL / 256, 256, 0, stream>>>(Wi, Wh, whi_sw, wlo_x);

    void* args[] = {(void*)&feats, (void*)&labels, (void*)&bi, (void*)&bh,
                    (void*)&Wd, (void*)&bd, (void*)&whi_sw, (void*)&wlo_x,
                    (void*)&h16, (void*)&xbuf, (void*)&ps_f32, (void*)&out,
                    (void*)&ctrl, (void*)&hflag, (void*)&pflag, (void*)&sflag};
    hipLaunchCooperativeKernel(reinterpret_cast<void*>(gru_main),
                               dim3(256), dim3(512), args, 0, stream);
}